// Round 1
// 3323.894 us; speedup vs baseline: 1.3477x; 1.3477x over previous
//
#include <hip/hip_runtime.h>

static constexpr int N_ = 32, V_ = 25, T_ = 64, C_ = 256;
static constexpr int S_ = 3, ST_ = 2, CI_ = 64, K_ = 7;
static constexpr int M_  = N_ * V_ * T_;          // 51200 rows (also N*T*V)
static constexpr int TC_ = T_ * C_;               // 16384
static constexpr int VC_ = V_ * C_;               // 6400
static constexpr long TOT_ = (long)M_ * C_;       // 13,107,200

__device__ __forceinline__ float gelu_f(float x) {
    return 0.5f * x * (1.0f + erff(x * 0.70710678118654752f));
}

__device__ __forceinline__ void fma44(float (&acc)[4][4], const float4& a, const float4& w) {
    const float av[4] = {a.x, a.y, a.z, a.w};
    const float wv[4] = {w.x, w.y, w.z, w.w};
    #pragma unroll
    for (int i = 0; i < 4; ++i)
        #pragma unroll
        for (int j = 0; j < 4; ++j) acc[i][j] += av[i] * wv[j];
}

// ---------------- tiled GEMM: Out(M,Nc) = A(M,Kc) @ W(Kc,Nc) (+bias) ----------
// 128x128 tile, BK=16, 256 threads, 8x8 outputs/thread (split 4+4 each dim).
// As staged k-major so fragment reads are contiguous float4 (ds_read_b128),
// split-64 column/row mapping keeps every LDS access <=2-way (free).
__global__ __launch_bounds__(256) void gemm_bias(
    const float* __restrict__ A, int lda,
    const float* __restrict__ W, int ldw,
    const float* __restrict__ bias,
    float* __restrict__ Out, int M, int Nc, int Kc)
{
    __shared__ float As[16][128];   // [k][m]
    __shared__ float Ws[16][128];   // [k][n]
    const int tid = threadIdx.x;
    const int tn = tid & 15, tm = tid >> 4;
    const int row0 = blockIdx.y * 128, col0 = blockIdx.x * 128;
    // staging coords
    const int ar = tid >> 1;            // 0..127 (A row within tile)
    const int ac = (tid & 1) * 8;       // 0 or 8 (A col within k-tile)
    const int wr = tid >> 4;            // 0..15  (W row within k-tile)
    const int wc = (tid & 15) * 4;      // 0..60  (W col, +64 twin)

    const float* arow = A + (long)(row0 + ar) * lda;
    const float* wrow = W + (long)wr * ldw + col0;

    float acc[2][2][4][4] = {};
    for (int k0 = 0; k0 < Kc; k0 += 16) {
        // prefetch globals (overlaps previous tile's compute)
        float4 a0 = *(const float4*)(arow + k0 + ac);
        float4 a1 = *(const float4*)(arow + k0 + ac + 4);
        const float* wp = wrow + (long)k0 * ldw;
        float4 w0 = *(const float4*)(wp + wc);
        float4 w1 = *(const float4*)(wp + 64 + wc);
        __syncthreads();
        As[ac + 0][ar] = a0.x; As[ac + 1][ar] = a0.y;
        As[ac + 2][ar] = a0.z; As[ac + 3][ar] = a0.w;
        As[ac + 4][ar] = a1.x; As[ac + 5][ar] = a1.y;
        As[ac + 6][ar] = a1.z; As[ac + 7][ar] = a1.w;
        *(float4*)&Ws[wr][wc]      = w0;
        *(float4*)&Ws[wr][64 + wc] = w1;
        __syncthreads();
        #pragma unroll
        for (int kk = 0; kk < 16; ++kk) {
            float4 aA = *(const float4*)&As[kk][tm * 4];
            float4 aB = *(const float4*)&As[kk][64 + tm * 4];
            float4 wA = *(const float4*)&Ws[kk][tn * 4];
            float4 wB = *(const float4*)&Ws[kk][64 + tn * 4];
            fma44(acc[0][0], aA, wA); fma44(acc[0][1], aA, wB);
            fma44(acc[1][0], aB, wA); fma44(acc[1][1], aB, wB);
        }
    }
    #pragma unroll
    for (int mi = 0; mi < 2; ++mi)
        #pragma unroll
        for (int i = 0; i < 4; ++i) {
            long r = row0 + mi * 64 + tm * 4 + i;
            #pragma unroll
            for (int ni = 0; ni < 2; ++ni) {
                int c = col0 + ni * 64 + tn * 4;
                float4 o;
                o.x = acc[mi][ni][i][0] + (bias ? bias[c + 0] : 0.0f);
                o.y = acc[mi][ni][i][1] + (bias ? bias[c + 1] : 0.0f);
                o.z = acc[mi][ni][i][2] + (bias ? bias[c + 2] : 0.0f);
                o.w = acc[mi][ni][i][3] + (bias ? bias[c + 3] : 0.0f);
                *(float4*)&Out[r * Nc + c] = o;
            }
        }
}

// ---------------- small utility kernels ---------------------------------------
__global__ void zero_f32(float* __restrict__ p, int n) {
    int i = blockIdx.x * 256 + threadIdx.x;
    if (i < n) p[i] = 0.0f;
}
__global__ void bcast_bias(const float* __restrict__ b, float* __restrict__ P, int total) {
    int i = blockIdx.x * 256 + threadIdx.x;
    if (i < total) P[i] = b[i & (C_ - 1)];
}
__global__ void repack_conv(const float* __restrict__ cw, float* __restrict__ out) {
    // cw: (O=256, I=256, K=7)  ->  out: (K, I, O)
    int idx = blockIdx.x * 256 + threadIdx.x;
    if (idx >= C_ * C_ * K_) return;
    int o = idx / (C_ * K_);
    int rem = idx % (C_ * K_);
    int i = rem / K_, kh = rem % K_;
    out[((long)kh * C_ + i) * C_ + o] = cw[idx];
}

// ---------------- spatial attention scores ------------------------------------
__global__ __launch_bounds__(256) void att_s_partial(
    const float* __restrict__ QK,     // (N,V,T,384)
    float* __restrict__ attPre)       // (N,V,V,S) zero-init
{
    const int n = blockIdx.x;
    const int tg = blockIdx.y;        // 0..7, 8 t's each
    __shared__ float lds[V_ * 384];   // 9600 floats
    const int NOUT = V_ * V_ * S_;    // 1875
    float acc[8] = {};
    for (int ttc = 0; ttc < 8; ++ttc) {
        int t = tg * 8 + ttc;
        __syncthreads();
        for (int l = threadIdx.x; l < V_ * 384; l += 256) {
            int v = l / 384, j = l % 384;
            lds[l] = QK[(((long)n * V_ + v) * T_ + t) * 384 + j];
        }
        __syncthreads();
        int ai = 0;
        for (int o = threadIdx.x; o < NOUT; o += 256, ++ai) {
            int u = o / (V_ * S_), rem = o % (V_ * S_), v = rem / S_, s = rem % S_;
            const float* qp = &lds[u * 384 + s];
            const float* kp = &lds[v * 384 + S_ + s];
            float sum = 0.f;
            #pragma unroll 8
            for (int ci = 0; ci < CI_; ++ci) sum += qp[ci * 6] * kp[ci * 6];
            acc[ai] += sum;
        }
    }
    int ai = 0;
    for (int o = threadIdx.x; o < NOUT; o += 256, ++ai)
        atomicAdd(&attPre[(long)n * NOUT + o], acc[ai]);
}

__global__ void att_s_final(const float* __restrict__ attPre,
                            const float* __restrict__ alphas,
                            const float* __restrict__ att0,
                            float* __restrict__ attS) {
    int idx = blockIdx.x * 256 + threadIdx.x;
    if (idx >= N_ * V_ * V_ * S_) return;
    int o = idx % (V_ * V_ * S_);
    int s = o % S_;
    attS[idx] = tanhf(attPre[idx] * (1.0f / (CI_ * T_))) * alphas[s] + att0[o];
}

// ---------------- spatial mixing ----------------------------------------------
__global__ __launch_bounds__(256) void vmix(
    const float* __restrict__ T1,     // (N,V,TC)
    const float* __restrict__ attS,   // (N,V,V,S)
    int s, float* __restrict__ P)     // (N,V,TC)
{
    const int n = blockIdx.y;
    const int col = blockIdx.x * 256 + threadIdx.x;   // 0..TC-1
    __shared__ float a[V_ * V_];
    for (int l = threadIdx.x; l < V_ * V_; l += 256)
        a[l] = attS[((long)n * V_ * V_ + l) * S_ + s];
    __syncthreads();
    float acc[V_] = {};
    for (int u = 0; u < V_; ++u) {
        float val = T1[((long)n * V_ + u) * TC_ + col];
        #pragma unroll
        for (int v = 0; v < V_; ++v) acc[v] += a[u * V_ + v] * val;
    }
    for (int v = 0; v < V_; ++v)
        P[((long)n * V_ + v) * TC_ + col] += acc[v];
}

// ---------------- temporal attention scores -----------------------------------
__global__ __launch_bounds__(256) void att_t(
    const float* __restrict__ QKT,    // (N,T,V,512)
    const float* __restrict__ alphat_f, const float* __restrict__ alphat_b,
    float* __restrict__ attF, float* __restrict__ attB)   // (N,2,T,T) [t][q]
{
    const int n = blockIdx.z;
    const int t0 = blockIdx.y * 16, q0 = blockIdx.x * 16;
    __shared__ float Qs[16 * 256], Ks[16 * 256];
    const int tt = threadIdx.x / 16, qq = threadIdx.x % 16;
    float acc[4] = {};
    for (int v = 0; v < V_; ++v) {
        for (int h = 0; h < 2; ++h) {
            __syncthreads();
            for (int l = threadIdx.x; l < 16 * 256; l += 256) {
                int r = l >> 8, c = l & 255;
                Qs[l] = QKT[(((long)n * T_ + t0 + r) * V_ + v) * 512 + h * 256 + c];
                Ks[l] = QKT[(((long)n * T_ + q0 + r) * V_ + v) * 512 + h * 256 + c];
            }
            __syncthreads();
            #pragma unroll 8
            for (int ci = 0; ci < 32; ++ci) {
                const float* qp = &Qs[tt * 256 + ci * 8];
                const float* kp = &Ks[qq * 256 + ci * 8];
                acc[0] += qp[0] * kp[4];
                acc[1] += qp[1] * kp[5];
                acc[2] += qp[2] * kp[6];
                acc[3] += qp[3] * kp[7];
            }
        }
    }
    const int t = t0 + tt, q = q0 + qq;
    const float mf = (t >= q) ? 1.0f : 0.0f;   // bmask.T
    const float mb = (q >= t) ? 1.0f : 0.0f;   // bmask
    const float inv = 1.0f / (CI_ * V_);
    for (int s = 0; s < 2; ++s) {
        attF[(((long)n * 2 + s) * T_ + t) * T_ + q] = tanhf(acc[s]     * inv) * alphat_f[s] * mf;
        attB[(((long)n * 2 + s) * T_ + t) * T_ + q] = tanhf(acc[2 + s] * inv) * alphat_b[s] * mb;
    }
}

// ---------------- temporal mixing ---------------------------------------------
__global__ __launch_bounds__(256) void tmix(
    const float* __restrict__ T1,     // (N,T,VC)
    const float* __restrict__ attX,   // (N,2,T,T)
    int s, float* __restrict__ P)     // (N,T,VC)
{
    const int n = blockIdx.y;
    const int col = blockIdx.x * 64 + (threadIdx.x & 63);  // 0..VC-1
    const int ty = threadIdx.x >> 6;                       // 0..3
    __shared__ float a[T_ * T_];
    for (int l = threadIdx.x; l < T_ * T_; l += 256)
        a[l] = attX[((long)n * 2 + s) * (T_ * T_) + l];
    __syncthreads();
    float acc[16] = {};
    for (int t = 0; t < T_; ++t) {
        float val = T1[((long)n * T_ + t) * VC_ + col];
        const float* ar = &a[t * T_ + ty * 16];
        #pragma unroll
        for (int i = 0; i < 16; ++i) acc[i] += ar[i] * val;
    }
    for (int i = 0; i < 16; ++i) {
        int q = ty * 16 + i;
        P[((long)n * T_ + q) * VC_ + col] += acc[i];
    }
}

// ---------------- LayerNorm over (T,C) per (n,v) ------------------------------
template <bool TR>
__global__ __launch_bounds__(256) void ln_res_gelu_TC(
    const float* __restrict__ P, const float* __restrict__ X,
    const float* __restrict__ G, const float* __restrict__ B,
    float* __restrict__ Out)
{
    const int g = blockIdx.x;          // n*V+v
    const int n = g / V_, v = g % V_;
    const float* p = P + (long)g * TC_;
    const float* x = X + (long)g * TC_;
    float s = 0.f, ss = 0.f;
    for (int i = threadIdx.x; i < TC_; i += 256) { float a = p[i]; s += a; ss += a * a; }
    __shared__ float rs[4], rss[4];
    #pragma unroll
    for (int off = 32; off > 0; off >>= 1) { s += __shfl_down(s, off); ss += __shfl_down(ss, off); }
    if ((threadIdx.x & 63) == 0) { rs[threadIdx.x >> 6] = s; rss[threadIdx.x >> 6] = ss; }
    __syncthreads();
    s = rs[0] + rs[1] + rs[2] + rs[3];
    ss = rss[0] + rss[1] + rss[2] + rss[3];
    const float mean = s * (1.0f / TC_);
    const float var  = ss * (1.0f / TC_) - mean * mean;
    const float rstd = rsqrtf(var + 1e-5f);
    for (int i = threadIdx.x; i < TC_; i += 256) {
        float val = (p[i] - mean) * rstd * G[i] + B[i];
        float r = gelu_f(x[i] + val);
        if (TR) {
            int t = i >> 8, c = i & 255;
            Out[(((long)n * T_ + t) * V_ + v) * C_ + c] = r;   // write (N,T,V,C)
        } else {
            Out[(long)g * TC_ + i] = r;
        }
    }
}

// ---------------- LayerNorm over (V,C) per (n,t) ------------------------------
__global__ __launch_bounds__(256) void ln_res_gelu_VC(
    const float* __restrict__ P, const float* __restrict__ X,
    const float* __restrict__ G, const float* __restrict__ B,
    float* __restrict__ Out)
{
    const int g = blockIdx.x;          // n*T+t
    const float* p = P + (long)g * VC_;
    const float* x = X + (long)g * VC_;
    float s = 0.f, ss = 0.f;
    for (int i = threadIdx.x; i < VC_; i += 256) { float a = p[i]; s += a; ss += a * a; }
    __shared__ float rs[4], rss[4];
    #pragma unroll
    for (int off = 32; off > 0; off >>= 1) { s += __shfl_down(s, off); ss += __shfl_down(ss, off); }
    if ((threadIdx.x & 63) == 0) { rs[threadIdx.x >> 6] = s; rss[threadIdx.x >> 6] = ss; }
    __syncthreads();
    s = rs[0] + rs[1] + rs[2] + rs[3];
    ss = rss[0] + rss[1] + rss[2] + rss[3];
    const float mean = s * (1.0f / VC_);
    const float var  = ss * (1.0f / VC_) - mean * mean;
    const float rstd = rsqrtf(var + 1e-5f);
    for (int i = threadIdx.x; i < VC_; i += 256) {
        float val = (p[i] - mean) * rstd * G[i] + B[i];
        Out[(long)g * VC_ + i] = gelu_f(x[i] + val);
    }
}

// ---------------- conv(7x1 over T) + BN + residual + gelu + final transpose ---
// Same 128x128 / 8x8-per-thread structure as gemm_bias, K-loop = 7 taps x 256.
__global__ __launch_bounds__(256) void conv_bn_gelu(
    const float* __restrict__ Z,      // (N,T,V,C)
    const float* __restrict__ Wc,     // (K,I,O) repacked
    const float* __restrict__ conv_b, const float* __restrict__ bn_g,
    const float* __restrict__ bn_b,  const float* __restrict__ bn_m,
    const float* __restrict__ bn_v,
    float* __restrict__ Out)          // (N,V,T,C)
{
    __shared__ float As[16][128];
    __shared__ float Ws[16][128];
    const int tid = threadIdx.x;
    const int tn = tid & 15, tm = tid >> 4;
    const int row0 = blockIdx.y * 128, col0 = blockIdx.x * 128;
    const int ar = tid >> 1;
    const int ac = (tid & 1) * 8;
    const int wr = tid >> 4;
    const int wc = (tid & 15) * 4;

    const int am = row0 + ar;
    const int at = (am / V_) % T_;    // t for this staging row (hoisted)

    float acc[2][2][4][4] = {};
    for (int kh = 0; kh < K_; ++kh) {
        const int d = kh - 3;
        const int t2 = at + d;
        const bool ok = (t2 >= 0) && (t2 < T_);
        const float* zrow = Z + (long)(am + d * V_) * C_;
        const float* wrow = Wc + ((long)kh * C_ + wr) * C_ + col0;
        for (int k0 = 0; k0 < C_; k0 += 16) {
            float4 a0 = {0, 0, 0, 0}, a1 = {0, 0, 0, 0};
            if (ok) {
                a0 = *(const float4*)(zrow + k0 + ac);
                a1 = *(const float4*)(zrow + k0 + ac + 4);
            }
            const float* wp = wrow + (long)k0 * C_;
            float4 w0 = *(const float4*)(wp + wc);
            float4 w1 = *(const float4*)(wp + 64 + wc);
            __syncthreads();
            As[ac + 0][ar] = a0.x; As[ac + 1][ar] = a0.y;
            As[ac + 2][ar] = a0.z; As[ac + 3][ar] = a0.w;
            As[ac + 4][ar] = a1.x; As[ac + 5][ar] = a1.y;
            As[ac + 6][ar] = a1.z; As[ac + 7][ar] = a1.w;
            *(float4*)&Ws[wr][wc]      = w0;
            *(float4*)&Ws[wr][64 + wc] = w1;
            __syncthreads();
            #pragma unroll
            for (int kk = 0; kk < 16; ++kk) {
                float4 aA = *(const float4*)&As[kk][tm * 4];
                float4 aB = *(const float4*)&As[kk][64 + tm * 4];
                float4 wA = *(const float4*)&Ws[kk][tn * 4];
                float4 wB = *(const float4*)&Ws[kk][64 + tn * 4];
                fma44(acc[0][0], aA, wA); fma44(acc[0][1], aA, wB);
                fma44(acc[1][0], aB, wA); fma44(acc[1][1], aB, wB);
            }
        }
    }
    #pragma unroll
    for (int mi = 0; mi < 2; ++mi)
        #pragma unroll
        for (int i = 0; i < 4; ++i) {
            int m = row0 + mi * 64 + tm * 4 + i;
            int n = m / (T_ * V_);
            int rem = m % (T_ * V_);
            int t = rem / V_, v = rem % V_;
            #pragma unroll
            for (int ni = 0; ni < 2; ++ni) {
                int c = col0 + ni * 64 + tn * 4;
                float4 res = *(const float4*)&Z[(long)m * C_ + c];
                float4 o;
                #pragma unroll
                for (int j = 0; j < 4; ++j) {
                    int oc = c + j;
                    float cv = acc[mi][ni][i][j] + conv_b[oc];
                    float bn = (cv - bn_m[oc]) * rsqrtf(bn_v[oc] + 1e-5f) * bn_g[oc] + bn_b[oc];
                    float rv = (j == 0) ? res.x : (j == 1) ? res.y : (j == 2) ? res.z : res.w;
                    ((float*)&o)[j] = gelu_f(rv + bn);
                }
                *(float4*)&Out[(((long)n * V_ + v) * T_ + t) * C_ + c] = o;
            }
        }
}

// ==============================================================================
extern "C" void kernel_launch(void* const* d_in, const int* in_sizes, int n_in,
                              void* d_out, int out_size, void* d_ws, size_t ws_size,
                              hipStream_t stream)
{
    const float* x        = (const float*)d_in[0];
    const float* Wqk_s    = (const float*)d_in[1];
    const float* bqk_s    = (const float*)d_in[2];
    const float* alphas   = (const float*)d_in[3];
    const float* att0s    = (const float*)d_in[4];
    const float* Wo_s     = (const float*)d_in[5];
    const float* bo_s     = (const float*)d_in[6];
    const float* g_os     = (const float*)d_in[7];
    const float* b_os     = (const float*)d_in[8];
    const float* Wff_s    = (const float*)d_in[9];
    const float* bff_s    = (const float*)d_in[10];
    const float* g_ffs    = (const float*)d_in[11];
    const float* b_ffs    = (const float*)d_in[12];
    const float* Wqk_t    = (const float*)d_in[13];
    const float* bqk_t    = (const float*)d_in[14];
    const float* alphat_f = (const float*)d_in[15];
    const float* alphat_b = (const float*)d_in[16];
    const float* Wo_t     = (const float*)d_in[17];
    const float* bo_t     = (const float*)d_in[18];
    const float* g_ot     = (const float*)d_in[19];
    const float* b_ot     = (const float*)d_in[20];
    const float* Wff_t    = (const float*)d_in[21];
    const float* bff_t    = (const float*)d_in[22];
    const float* g_fft    = (const float*)d_in[23];
    const float* b_fft    = (const float*)d_in[24];
    const float* conv_w   = (const float*)d_in[25];
    const float* conv_b   = (const float*)d_in[26];
    const float* bn_g     = (const float*)d_in[27];
    const float* bn_b     = (const float*)d_in[28];
    const float* bn_m     = (const float*)d_in[29];
    const float* bn_v     = (const float*)d_in[30];

    float* ws = (float*)d_ws;
    float* R1 = ws;                         // 26,214,400 f (qk / qkt / Z)
    float* R2 = R1 + (long)N_*T_*V_*512;    // 13,107,200 f (P accum)
    float* R3 = R2 + TOT_;                  // 13,107,200 f (T1 / Y / Z2)
    float* RA = R3 + TOT_;
    float* attPre = RA;                               // 60,000
    float* attS   = attPre + N_*V_*V_*S_;             // 60,000
    float* attF   = attS   + N_*V_*V_*S_;             // 262,144
    float* attB   = attF   + (long)N_*2*T_*T_;        // 262,144
    float* convW  = attB   + (long)N_*2*T_*T_;        // 458,752
    float* YT = (float*)d_out;              // y^T (N,T,V,C); overwritten at the end

    const int TOT_I = (int)TOT_;

    // ---- Stage 1: spatial ----
    // qk = x @ Wqk_s + bqk_s
    gemm_bias<<<dim3(384/128, M_/128), 256, 0, stream>>>(x, C_, Wqk_s, 2*S_*CI_, bqk_s, R1, M_, 2*S_*CI_, C_);
    // att_s
    zero_f32<<<(N_*V_*V_*S_ + 255)/256, 256, 0, stream>>>(attPre, N_*V_*V_*S_);
    att_s_partial<<<dim3(N_, 8), 256, 0, stream>>>(R1, attPre);
    att_s_final<<<(N_*V_*V_*S_ + 255)/256, 256, 0, stream>>>(attPre, alphas, att0s, attS);
    // P = bo_s + sum_s attmix_s(x @ Wo_block_s)
    bcast_bias<<<(TOT_I + 255)/256, 256, 0, stream>>>(bo_s, R2, TOT_I);
    for (int s = 0; s < S_; ++s) {
        gemm_bias<<<dim3(C_/128, M_/128), 256, 0, stream>>>(x, C_, Wo_s + s*C_, S_*C_, nullptr, R3, M_, C_, C_);
        vmix<<<dim3(TC_/256, N_), 256, 0, stream>>>(R3, attS, s, R2);
    }
    // Y = gelu(x + ln(P))
    ln_res_gelu_TC<false><<<N_*V_, 256, 0, stream>>>(R2, x, g_os, b_os, R3);
    // P2 = Y @ Wff_s + bff_s ; YT = gelu(x + ln(P2)) transposed to (N,T,V,C)
    gemm_bias<<<dim3(C_/128, M_/128), 256, 0, stream>>>(R3, C_, Wff_s, C_, bff_s, R2, M_, C_, C_);
    ln_res_gelu_TC<true><<<N_*V_, 256, 0, stream>>>(R2, x, g_ffs, b_ffs, YT);

    // ---- Stage 2: temporal ----
    gemm_bias<<<dim3(512/128, M_/128), 256, 0, stream>>>(YT, C_, Wqk_t, 4*ST_*CI_, bqk_t, R1, M_, 4*ST_*CI_, C_);
    att_t<<<dim3(4, 4, N_), 256, 0, stream>>>(R1, alphat_f, alphat_b, attF, attB);
    bcast_bias<<<(TOT_I + 255)/256, 256, 0, stream>>>(bo_t, R2, TOT_I);
    for (int s = 0; s < ST_; ++s) {
        // forward block: Wo_t rows c*ST+s
        gemm_bias<<<dim3(C_/128, M_/128), 256, 0, stream>>>(YT, C_, Wo_t + s*C_, ST_*C_, nullptr, R3, M_, C_, C_);
        tmix<<<dim3(VC_/64, N_), 256, 0, stream>>>(R3, attF, s, R2);
        // backward block: Wo_t rows ST*C + c*ST+s
        gemm_bias<<<dim3(C_/128, M_/128), 256, 0, stream>>>(YT, C_, Wo_t + (long)ST_*C_*C_ + s*C_, ST_*C_, nullptr, R3, M_, C_, C_);
        tmix<<<dim3(VC_/64, N_), 256, 0, stream>>>(R3, attB, s, R2);
    }
    // Z = gelu(yT + ln(P))
    ln_res_gelu_VC<<<N_*T_, 256, 0, stream>>>(R2, YT, g_ot, b_ot, R1);
    // P2 = Z @ Wff_t + bff_t ; Z2 = gelu(yT + ln(P2))
    gemm_bias<<<dim3(C_/128, M_/128), 256, 0, stream>>>(R1, C_, Wff_t, C_, bff_t, R2, M_, C_, C_);
    ln_res_gelu_VC<<<N_*T_, 256, 0, stream>>>(R2, YT, g_fft, b_fft, R3);

    // ---- Stage 3: conv + BN + gelu + transpose ----
    repack_conv<<<(C_*C_*K_ + 255)/256, 256, 0, stream>>>(conv_w, convW);
    conv_bn_gelu<<<dim3(C_/128, M_/128), 256, 0, stream>>>(R3, convW, conv_b, bn_g, bn_b, bn_m, bn_v, (float*)d_out);
}

// Round 2
// 2988.900 us; speedup vs baseline: 1.4987x; 1.1121x over previous
//
#include <hip/hip_runtime.h>

static constexpr int N_ = 32, V_ = 25, T_ = 64, C_ = 256;
static constexpr int S_ = 3, ST_ = 2, CI_ = 64, K_ = 7;
static constexpr int M_  = N_ * V_ * T_;          // 51200 rows (also N*T*V)
static constexpr int TC_ = T_ * C_;               // 16384
static constexpr int VC_ = V_ * C_;               // 6400
static constexpr long TOT_ = (long)M_ * C_;       // 13,107,200

__device__ __forceinline__ float gelu_f(float x) {
    return 0.5f * x * (1.0f + erff(x * 0.70710678118654752f));
}

__device__ __forceinline__ void fma44(float (&acc)[4][4], const float4& a, const float4& w) {
    const float av[4] = {a.x, a.y, a.z, a.w};
    const float wv[4] = {w.x, w.y, w.z, w.w};
    #pragma unroll
    for (int i = 0; i < 4; ++i)
        #pragma unroll
        for (int j = 0; j < 4; ++j) acc[i][j] += av[i] * wv[j];
}

// ---------------- tiled GEMM: Out(M,Nc) = A(M,Kc) @ W(Kc,Nc) (+bias) ----------
// 128x128 tile, BK=16, 256 threads, 8x8 outputs/thread.
// Reg-staged pipeline: next tile's global loads issue BEFORE the current tile's
// FMA block, so L2/HBM latency hides under 2048 cy of compute.
__global__ __launch_bounds__(256) void gemm_bias(
    const float* __restrict__ A, int lda,
    const float* __restrict__ W, int ldw,
    const float* __restrict__ bias,
    float* __restrict__ Out, int M, int Nc, int Kc)
{
    __shared__ float As[16][128];   // [k][m]
    __shared__ float Ws[16][128];   // [k][n]
    const int tid = threadIdx.x;
    const int tn = tid & 15, tm = tid >> 4;
    const int row0 = blockIdx.y * 128, col0 = blockIdx.x * 128;
    const int ar = tid >> 1;            // 0..127 (A row within tile)
    const int ac = (tid & 1) * 8;       // 0 or 8 (A col within k-tile)
    const int wr = tid >> 4;            // 0..15  (W row within k-tile)
    const int wc = (tid & 15) * 4;      // 0..60  (W col, +64 twin)

    const float* arow = A + (long)(row0 + ar) * lda;
    const float* wrow = W + (long)wr * ldw + col0;

    // prologue prefetch (k0 = 0)
    float4 a0 = *(const float4*)(arow + ac);
    float4 a1 = *(const float4*)(arow + ac + 4);
    float4 w0 = *(const float4*)(wrow + wc);
    float4 w1 = *(const float4*)(wrow + 64 + wc);

    float acc[2][2][4][4] = {};
    for (int k0 = 0; k0 < Kc; k0 += 16) {
        __syncthreads();
        As[ac + 0][ar] = a0.x; As[ac + 1][ar] = a0.y;
        As[ac + 2][ar] = a0.z; As[ac + 3][ar] = a0.w;
        As[ac + 4][ar] = a1.x; As[ac + 5][ar] = a1.y;
        As[ac + 6][ar] = a1.z; As[ac + 7][ar] = a1.w;
        *(float4*)&Ws[wr][wc]      = w0;
        *(float4*)&Ws[wr][64 + wc] = w1;
        __syncthreads();
        const int kn = k0 + 16;
        if (kn < Kc) {   // issue next tile's loads; they fly under the FMAs below
            a0 = *(const float4*)(arow + kn + ac);
            a1 = *(const float4*)(arow + kn + ac + 4);
            const float* wp = wrow + (long)kn * ldw;
            w0 = *(const float4*)(wp + wc);
            w1 = *(const float4*)(wp + 64 + wc);
        }
        #pragma unroll
        for (int kk = 0; kk < 16; ++kk) {
            float4 aA = *(const float4*)&As[kk][tm * 4];
            float4 aB = *(const float4*)&As[kk][64 + tm * 4];
            float4 wA = *(const float4*)&Ws[kk][tn * 4];
            float4 wB = *(const float4*)&Ws[kk][64 + tn * 4];
            fma44(acc[0][0], aA, wA); fma44(acc[0][1], aA, wB);
            fma44(acc[1][0], aB, wA); fma44(acc[1][1], aB, wB);
        }
    }
    #pragma unroll
    for (int mi = 0; mi < 2; ++mi)
        #pragma unroll
        for (int i = 0; i < 4; ++i) {
            long r = row0 + mi * 64 + tm * 4 + i;
            #pragma unroll
            for (int ni = 0; ni < 2; ++ni) {
                int c = col0 + ni * 64 + tn * 4;
                float4 o;
                o.x = acc[mi][ni][i][0] + (bias ? bias[c + 0] : 0.0f);
                o.y = acc[mi][ni][i][1] + (bias ? bias[c + 1] : 0.0f);
                o.z = acc[mi][ni][i][2] + (bias ? bias[c + 2] : 0.0f);
                o.w = acc[mi][ni][i][3] + (bias ? bias[c + 3] : 0.0f);
                *(float4*)&Out[r * Nc + c] = o;
            }
        }
}

// ---------------- small utility kernels ---------------------------------------
__global__ void zero_f32(float* __restrict__ p, int n) {
    int i = blockIdx.x * 256 + threadIdx.x;
    if (i < n) p[i] = 0.0f;
}
__global__ void repack_conv(const float* __restrict__ cw, float* __restrict__ out) {
    // cw: (O=256, I=256, K=7)  ->  out: (K, I, O)
    int idx = blockIdx.x * 256 + threadIdx.x;
    if (idx >= C_ * C_ * K_) return;
    int o = idx / (C_ * K_);
    int rem = idx % (C_ * K_);
    int i = rem / K_, kh = rem % K_;
    out[((long)kh * C_ + i) * C_ + o] = cw[idx];
}

// ---------------- spatial attention scores ------------------------------------
__global__ __launch_bounds__(256) void att_s_partial(
    const float* __restrict__ QK,     // (N,V,T,384)
    float* __restrict__ attPre)       // (N,V,V,S) zero-init
{
    const int n = blockIdx.x;
    const int tg = blockIdx.y;        // 0..7, 8 t's each
    __shared__ float lds[V_ * 384];   // 9600 floats
    const int NOUT = V_ * V_ * S_;    // 1875
    float acc[8] = {};
    for (int ttc = 0; ttc < 8; ++ttc) {
        int t = tg * 8 + ttc;
        __syncthreads();
        for (int l = threadIdx.x; l < V_ * 384; l += 256) {
            int v = l / 384, j = l % 384;
            lds[l] = QK[(((long)n * V_ + v) * T_ + t) * 384 + j];
        }
        __syncthreads();
        int ai = 0;
        for (int o = threadIdx.x; o < NOUT; o += 256, ++ai) {
            int u = o / (V_ * S_), rem = o % (V_ * S_), v = rem / S_, s = rem % S_;
            const float* qp = &lds[u * 384 + s];
            const float* kp = &lds[v * 384 + S_ + s];
            float sum = 0.f;
            #pragma unroll 8
            for (int ci = 0; ci < CI_; ++ci) sum += qp[ci * 6] * kp[ci * 6];
            acc[ai] += sum;
        }
    }
    int ai = 0;
    for (int o = threadIdx.x; o < NOUT; o += 256, ++ai)
        atomicAdd(&attPre[(long)n * NOUT + o], acc[ai]);
}

__global__ void att_s_final(const float* __restrict__ attPre,
                            const float* __restrict__ alphas,
                            const float* __restrict__ att0,
                            float* __restrict__ attS) {
    int idx = blockIdx.x * 256 + threadIdx.x;
    if (idx >= N_ * V_ * V_ * S_) return;
    int o = idx % (V_ * V_ * S_);
    int s = o % S_;
    attS[idx] = tanhf(attPre[idx] * (1.0f / (CI_ * T_))) * alphas[s] + att0[o];
}

// ---------------- fused spatial mixing ----------------------------------------
// P[n,v,t,c] = bo[c] + sum_{u,s} attS[n,u,v,s] * G[(n*V+u)*T+t, s*256+c]
__global__ __launch_bounds__(256) void vmix_all(
    const float* __restrict__ G,      // (M, 768)
    const float* __restrict__ attS,   // (N,V,V,S)
    const float* __restrict__ bias,   // (C)
    float* __restrict__ P)            // (N,V,TC)
{
    const int n = blockIdx.y;
    const int t = blockIdx.x;         // 0..63
    const int c = threadIdx.x;        // 0..255
    __shared__ float a[3][V_ * V_];
    for (int l = threadIdx.x; l < V_ * V_ * S_; l += 256) {
        int uv = l / S_, s = l % S_;
        a[s][uv] = attS[((long)n * V_ * V_ + uv) * S_ + s];
    }
    __syncthreads();
    float acc[V_] = {};
    for (int u = 0; u < V_; ++u) {
        const float* g = G + ((long)((n * V_ + u) * T_) + t) * 768 + c;
        float v0 = g[0], v1 = g[256], v2 = g[512];
        const float* a0 = &a[0][u * V_], *a1 = &a[1][u * V_], *a2 = &a[2][u * V_];
        #pragma unroll
        for (int v = 0; v < V_; ++v)
            acc[v] += a0[v] * v0 + a1[v] * v1 + a2[v] * v2;
    }
    const float b = bias[c];
    for (int v = 0; v < V_; ++v)
        P[((long)(n * V_ + v) * T_ + t) * C_ + c] = acc[v] + b;
}

// ---------------- temporal attention scores -----------------------------------
__global__ __launch_bounds__(256) void att_t(
    const float* __restrict__ QKT,    // (N,T,V,512)
    const float* __restrict__ alphat_f, const float* __restrict__ alphat_b,
    float* __restrict__ attF, float* __restrict__ attB)   // (N,2,T,T) [t][q]
{
    const int n = blockIdx.z;
    const int t0 = blockIdx.y * 16, q0 = blockIdx.x * 16;
    __shared__ float Qs[16 * 256], Ks[16 * 256];
    const int tt = threadIdx.x / 16, qq = threadIdx.x % 16;
    float acc[4] = {};
    for (int v = 0; v < V_; ++v) {
        for (int h = 0; h < 2; ++h) {
            __syncthreads();
            for (int l = threadIdx.x; l < 16 * 256; l += 256) {
                int r = l >> 8, c = l & 255;
                Qs[l] = QKT[(((long)n * T_ + t0 + r) * V_ + v) * 512 + h * 256 + c];
                Ks[l] = QKT[(((long)n * T_ + q0 + r) * V_ + v) * 512 + h * 256 + c];
            }
            __syncthreads();
            #pragma unroll 8
            for (int ci = 0; ci < 32; ++ci) {
                const float* qp = &Qs[tt * 256 + ci * 8];
                const float* kp = &Ks[qq * 256 + ci * 8];
                acc[0] += qp[0] * kp[4];
                acc[1] += qp[1] * kp[5];
                acc[2] += qp[2] * kp[6];
                acc[3] += qp[3] * kp[7];
            }
        }
    }
    const int t = t0 + tt, q = q0 + qq;
    const float mf = (t >= q) ? 1.0f : 0.0f;   // bmask.T
    const float mb = (q >= t) ? 1.0f : 0.0f;   // bmask
    const float inv = 1.0f / (CI_ * V_);
    for (int s = 0; s < 2; ++s) {
        attF[(((long)n * 2 + s) * T_ + t) * T_ + q] = tanhf(acc[s]     * inv) * alphat_f[s] * mf;
        attB[(((long)n * 2 + s) * T_ + t) * T_ + q] = tanhf(acc[2 + s] * inv) * alphat_b[s] * mb;
    }
}

// ---------------- fused temporal mixing (one att pair, 2 s-slots) -------------
// INIT: P = bias + sum_{t,s} att[n,s,t,q] * G[(n*T+t)*V+v, s*256+c]
// else: P += sum_{t,s} ...
template <bool INIT>
__global__ __launch_bounds__(256) void tmix_all(
    const float* __restrict__ G,      // (M, 512) rows (n*T+t)*V+v
    const float* __restrict__ att,    // (N,2,T,T)
    const float* __restrict__ bias,   // (C) or null
    float* __restrict__ P)            // (N,T,VC)
{
    const int n = blockIdx.y;
    const int col = blockIdx.x * 64 + (threadIdx.x & 63);  // 0..VC-1
    const int ty = threadIdx.x >> 6;                       // 0..3
    const int v = col >> 8, c = col & 255;
    __shared__ float a[2 * T_ * T_];
    for (int l = threadIdx.x; l < 2 * T_ * T_; l += 256)
        a[l] = att[(long)n * 2 * T_ * T_ + l];
    __syncthreads();
    float acc[16] = {};
    for (int t = 0; t < T_; ++t) {
        const float* g = G + ((long)((n * T_ + t) * V_) + v) * 512 + c;
        float v0 = g[0], v1 = g[256];
        const float* ar0 = &a[t * T_ + ty * 16];
        const float* ar1 = ar0 + T_ * T_;
        #pragma unroll
        for (int i = 0; i < 16; ++i) acc[i] += ar0[i] * v0 + ar1[i] * v1;
    }
    for (int i = 0; i < 16; ++i) {
        int q = ty * 16 + i;
        long idx = ((long)n * T_ + q) * VC_ + col;
        if (INIT) P[idx] = acc[i] + bias[c];
        else      P[idx] += acc[i];
    }
}

// ---------------- LayerNorm over (T,C) per (n,v) ------------------------------
template <bool TR>
__global__ __launch_bounds__(256) void ln_res_gelu_TC(
    const float* __restrict__ P, const float* __restrict__ X,
    const float* __restrict__ G, const float* __restrict__ B,
    float* __restrict__ Out)
{
    const int g = blockIdx.x;          // n*V+v
    const int n = g / V_, v = g % V_;
    const float* p = P + (long)g * TC_;
    const float* x = X + (long)g * TC_;
    float s = 0.f, ss = 0.f;
    for (int i = threadIdx.x; i < TC_; i += 256) { float a = p[i]; s += a; ss += a * a; }
    __shared__ float rs[4], rss[4];
    #pragma unroll
    for (int off = 32; off > 0; off >>= 1) { s += __shfl_down(s, off); ss += __shfl_down(ss, off); }
    if ((threadIdx.x & 63) == 0) { rs[threadIdx.x >> 6] = s; rss[threadIdx.x >> 6] = ss; }
    __syncthreads();
    s = rs[0] + rs[1] + rs[2] + rs[3];
    ss = rss[0] + rss[1] + rss[2] + rss[3];
    const float mean = s * (1.0f / TC_);
    const float var  = ss * (1.0f / TC_) - mean * mean;
    const float rstd = rsqrtf(var + 1e-5f);
    for (int i = threadIdx.x; i < TC_; i += 256) {
        float val = (p[i] - mean) * rstd * G[i] + B[i];
        float r = gelu_f(x[i] + val);
        if (TR) {
            int t = i >> 8, c = i & 255;
            Out[(((long)n * T_ + t) * V_ + v) * C_ + c] = r;   // write (N,T,V,C)
        } else {
            Out[(long)g * TC_ + i] = r;
        }
    }
}

// ---------------- LayerNorm over (V,C) per (n,t) ------------------------------
__global__ __launch_bounds__(256) void ln_res_gelu_VC(
    const float* __restrict__ P, const float* __restrict__ X,
    const float* __restrict__ G, const float* __restrict__ B,
    float* __restrict__ Out)
{
    const int g = blockIdx.x;          // n*T+t
    const float* p = P + (long)g * VC_;
    const float* x = X + (long)g * VC_;
    float s = 0.f, ss = 0.f;
    for (int i = threadIdx.x; i < VC_; i += 256) { float a = p[i]; s += a; ss += a * a; }
    __shared__ float rs[4], rss[4];
    #pragma unroll
    for (int off = 32; off > 0; off >>= 1) { s += __shfl_down(s, off); ss += __shfl_down(ss, off); }
    if ((threadIdx.x & 63) == 0) { rs[threadIdx.x >> 6] = s; rss[threadIdx.x >> 6] = ss; }
    __syncthreads();
    s = rs[0] + rs[1] + rs[2] + rs[3];
    ss = rss[0] + rss[1] + rss[2] + rss[3];
    const float mean = s * (1.0f / VC_);
    const float var  = ss * (1.0f / VC_) - mean * mean;
    const float rstd = rsqrtf(var + 1e-5f);
    for (int i = threadIdx.x; i < VC_; i += 256) {
        float val = (p[i] - mean) * rstd * G[i] + B[i];
        Out[(long)g * VC_ + i] = gelu_f(x[i] + val);
    }
}

// ---------------- conv(7x1 over T) + BN + residual + gelu + final transpose ---
// Pipelined like gemm_bias; flattened (kh,k0) loop, next stage prefetched.
__global__ __launch_bounds__(256) void conv_bn_gelu(
    const float* __restrict__ Z,      // (N,T,V,C)
    const float* __restrict__ Wc,     // (K,I,O) repacked
    const float* __restrict__ conv_b, const float* __restrict__ bn_g,
    const float* __restrict__ bn_b,  const float* __restrict__ bn_m,
    const float* __restrict__ bn_v,
    float* __restrict__ Out)          // (N,V,T,C)
{
    __shared__ float As[16][128];
    __shared__ float Ws[16][128];
    const int tid = threadIdx.x;
    const int tn = tid & 15, tm = tid >> 4;
    const int row0 = blockIdx.y * 128, col0 = blockIdx.x * 128;
    const int ar = tid >> 1;
    const int ac = (tid & 1) * 8;
    const int wr = tid >> 4;
    const int wc = (tid & 15) * 4;

    const int am = row0 + ar;
    const int at = (am / V_) % T_;    // t for this staging row

    auto ldA = [&](int kh, int k0, float4& a0, float4& a1) {
        const int d = kh - 3;
        const int t2 = at + d;
        if (t2 >= 0 && t2 < T_) {
            const float* zr = Z + (long)(am + d * V_) * C_ + k0;
            a0 = *(const float4*)(zr + ac);
            a1 = *(const float4*)(zr + ac + 4);
        } else {
            a0 = make_float4(0, 0, 0, 0);
            a1 = make_float4(0, 0, 0, 0);
        }
    };
    auto ldW = [&](int kh, int k0, float4& w0, float4& w1) {
        const float* wp = Wc + ((long)kh * C_ + k0 + wr) * C_ + col0;
        w0 = *(const float4*)(wp + wc);
        w1 = *(const float4*)(wp + 64 + wc);
    };

    float4 a0, a1, w0, w1;
    ldA(0, 0, a0, a1);
    ldW(0, 0, w0, w1);

    float acc[2][2][4][4] = {};
    for (int kt = 0; kt < K_ * 16; ++kt) {          // 112 stages
        __syncthreads();
        As[ac + 0][ar] = a0.x; As[ac + 1][ar] = a0.y;
        As[ac + 2][ar] = a0.z; As[ac + 3][ar] = a0.w;
        As[ac + 4][ar] = a1.x; As[ac + 5][ar] = a1.y;
        As[ac + 6][ar] = a1.z; As[ac + 7][ar] = a1.w;
        *(float4*)&Ws[wr][wc]      = w0;
        *(float4*)&Ws[wr][64 + wc] = w1;
        __syncthreads();
        if (kt + 1 < K_ * 16) {
            const int kh = (kt + 1) >> 4, k0 = ((kt + 1) & 15) * 16;
            ldA(kh, k0, a0, a1);
            ldW(kh, k0, w0, w1);
        }
        #pragma unroll
        for (int kk = 0; kk < 16; ++kk) {
            float4 aA = *(const float4*)&As[kk][tm * 4];
            float4 aB = *(const float4*)&As[kk][64 + tm * 4];
            float4 wA = *(const float4*)&Ws[kk][tn * 4];
            float4 wB = *(const float4*)&Ws[kk][64 + tn * 4];
            fma44(acc[0][0], aA, wA); fma44(acc[0][1], aA, wB);
            fma44(acc[1][0], aB, wA); fma44(acc[1][1], aB, wB);
        }
    }
    #pragma unroll
    for (int mi = 0; mi < 2; ++mi)
        #pragma unroll
        for (int i = 0; i < 4; ++i) {
            int m = row0 + mi * 64 + tm * 4 + i;
            int n = m / (T_ * V_);
            int rem = m % (T_ * V_);
            int t = rem / V_, v = rem % V_;
            #pragma unroll
            for (int ni = 0; ni < 2; ++ni) {
                int c = col0 + ni * 64 + tn * 4;
                float4 res = *(const float4*)&Z[(long)m * C_ + c];
                float4 o;
                #pragma unroll
                for (int j = 0; j < 4; ++j) {
                    int oc = c + j;
                    float cv = acc[mi][ni][i][j] + conv_b[oc];
                    float bn = (cv - bn_m[oc]) * rsqrtf(bn_v[oc] + 1e-5f) * bn_g[oc] + bn_b[oc];
                    float rv = (j == 0) ? res.x : (j == 1) ? res.y : (j == 2) ? res.z : res.w;
                    ((float*)&o)[j] = gelu_f(rv + bn);
                }
                *(float4*)&Out[(((long)n * V_ + v) * T_ + t) * C_ + c] = o;
            }
        }
}

// ==============================================================================
extern "C" void kernel_launch(void* const* d_in, const int* in_sizes, int n_in,
                              void* d_out, int out_size, void* d_ws, size_t ws_size,
                              hipStream_t stream)
{
    const float* x        = (const float*)d_in[0];
    const float* Wqk_s    = (const float*)d_in[1];
    const float* bqk_s    = (const float*)d_in[2];
    const float* alphas   = (const float*)d_in[3];
    const float* att0s    = (const float*)d_in[4];
    const float* Wo_s     = (const float*)d_in[5];
    const float* bo_s     = (const float*)d_in[6];
    const float* g_os     = (const float*)d_in[7];
    const float* b_os     = (const float*)d_in[8];
    const float* Wff_s    = (const float*)d_in[9];
    const float* bff_s    = (const float*)d_in[10];
    const float* g_ffs    = (const float*)d_in[11];
    const float* b_ffs    = (const float*)d_in[12];
    const float* Wqk_t    = (const float*)d_in[13];
    const float* bqk_t    = (const float*)d_in[14];
    const float* alphat_f = (const float*)d_in[15];
    const float* alphat_b = (const float*)d_in[16];
    const float* Wo_t     = (const float*)d_in[17];
    const float* bo_t     = (const float*)d_in[18];
    const float* g_ot     = (const float*)d_in[19];
    const float* b_ot     = (const float*)d_in[20];
    const float* Wff_t    = (const float*)d_in[21];
    const float* bff_t    = (const float*)d_in[22];
    const float* g_fft    = (const float*)d_in[23];
    const float* b_fft    = (const float*)d_in[24];
    const float* conv_w   = (const float*)d_in[25];
    const float* conv_b   = (const float*)d_in[26];
    const float* bn_g     = (const float*)d_in[27];
    const float* bn_b     = (const float*)d_in[28];
    const float* bn_m     = (const float*)d_in[29];
    const float* bn_v     = (const float*)d_in[30];

    float* B  = (float*)d_ws;
    // big-region plan (floats), all within the 53.5M-float footprint:
    //   stage 1: G1/Gs at B0 (up to 39.3M) ; P at 39.3M ; Y at B0 ; P2 at 13.1M
    //   stage 2: QKT at B0 ; Gt at 26.2M ; Pt at B0 ; Z at 13.1M ; P2 at 26.2M ; Z2 at 39.3M
    float* B0  = B;
    float* B13 = B + TOT_;            // +13.1M
    float* B26 = B + 2 * TOT_;        // +26.2M
    float* B39 = B + 3 * TOT_;        // +39.3M
    float* RA  = B + 4 * TOT_;        // +52.4M small buffers
    float* attPre = RA;                               // 60,000
    float* attS   = attPre + N_*V_*V_*S_;             // 60,000
    float* attF   = attS   + N_*V_*V_*S_;             // 262,144
    float* attB   = attF   + (long)N_*2*T_*T_;        // 262,144
    float* convW  = attB   + (long)N_*2*T_*T_;        // 458,752
    float* YT = (float*)d_out;        // y^T (N,T,V,C); overwritten at the end

    // ---- Stage 1: spatial ----
    // qk = x @ Wqk_s + bqk_s   -> B0 (M x 384)
    gemm_bias<<<dim3(384/128, M_/128), 256, 0, stream>>>(x, C_, Wqk_s, 2*S_*CI_, bqk_s, B0, M_, 2*S_*CI_, C_);
    zero_f32<<<(N_*V_*V_*S_ + 255)/256, 256, 0, stream>>>(attPre, N_*V_*V_*S_);
    att_s_partial<<<dim3(N_, 8), 256, 0, stream>>>(B0, attPre);
    att_s_final<<<(N_*V_*V_*S_ + 255)/256, 256, 0, stream>>>(attPre, alphas, att0s, attS);
    // Gs = x @ Wo_s (fused all 3 s-blocks, Nc=768) -> B0 (M x 768)
    gemm_bias<<<dim3(768/128, M_/128), 256, 0, stream>>>(x, C_, Wo_s, S_*C_, nullptr, B0, M_, S_*C_, C_);
    // P = bo_s + sum_{u,s} att*Gs  -> B39
    vmix_all<<<dim3(T_, N_), 256, 0, stream>>>(B0, attS, bo_s, B39);
    // Y = gelu(x + ln(P)) -> B0
    ln_res_gelu_TC<false><<<N_*V_, 256, 0, stream>>>(B39, x, g_os, b_os, B0);
    // P2 = Y @ Wff_s + bff_s -> B13 ; YT = gelu(x + ln(P2)) transposed
    gemm_bias<<<dim3(C_/128, M_/128), 256, 0, stream>>>(B0, C_, Wff_s, C_, bff_s, B13, M_, C_, C_);
    ln_res_gelu_TC<true><<<N_*V_, 256, 0, stream>>>(B13, x, g_ffs, b_ffs, YT);

    // ---- Stage 2: temporal ----
    // QKT = YT @ Wqk_t + bqk_t -> B0 (M x 512)
    gemm_bias<<<dim3(512/128, M_/128), 256, 0, stream>>>(YT, C_, Wqk_t, 4*ST_*CI_, bqk_t, B0, M_, 4*ST_*CI_, C_);
    att_t<<<dim3(4, 4, N_), 256, 0, stream>>>(B0, alphat_f, alphat_b, attF, attB);
    // Gt0 = YT @ Wo_t[h=0] (Nc=512) -> B26 ; Pt = bo_t + mixF -> B0
    gemm_bias<<<dim3(512/128, M_/128), 256, 0, stream>>>(YT, C_, Wo_t, ST_*C_, nullptr, B26, M_, ST_*C_, C_);
    tmix_all<true><<<dim3(VC_/64, N_), 256, 0, stream>>>(B26, attF, bo_t, B0);
    // Gt1 = YT @ Wo_t[h=1] -> B26 ; Pt += mixB
    gemm_bias<<<dim3(512/128, M_/128), 256, 0, stream>>>(YT, C_, Wo_t + (long)ST_*C_*C_, ST_*C_, nullptr, B26, M_, ST_*C_, C_);
    tmix_all<false><<<dim3(VC_/64, N_), 256, 0, stream>>>(B26, attB, nullptr, B0);
    // Z = gelu(yT + ln(Pt)) -> B13
    ln_res_gelu_VC<<<N_*T_, 256, 0, stream>>>(B0, YT, g_ot, b_ot, B13);
    // P2 = Z @ Wff_t + bff_t -> B26 ; Z2 = gelu(yT + ln(P2)) -> B39
    gemm_bias<<<dim3(C_/128, M_/128), 256, 0, stream>>>(B13, C_, Wff_t, C_, bff_t, B26, M_, C_, C_);
    ln_res_gelu_VC<<<N_*T_, 256, 0, stream>>>(B26, YT, g_fft, b_fft, B39);

    // ---- Stage 3: conv + BN + gelu + transpose ----
    repack_conv<<<(C_*C_*K_ + 255)/256, 256, 0, stream>>>(conv_w, convW);
    conv_bn_gelu<<<dim3(C_/128, M_/128), 256, 0, stream>>>(B39, convW, conv_b, bn_g, bn_b, bn_m, bn_v, (float*)d_out);
}

// Round 3
// 1934.700 us; speedup vs baseline: 2.3154x; 1.5449x over previous
//
#include <hip/hip_runtime.h>

static constexpr int N_ = 32, V_ = 25, T_ = 64, C_ = 256;
static constexpr int S_ = 3, ST_ = 2, CI_ = 64, K_ = 7;
static constexpr int M_  = N_ * V_ * T_;          // 51200 rows (also N*T*V)
static constexpr int TC_ = T_ * C_;               // 16384
static constexpr int VC_ = V_ * C_;               // 6400
static constexpr long TOT_ = (long)M_ * C_;       // 13,107,200

typedef __bf16 bf16x8 __attribute__((ext_vector_type(8)));
typedef float  f32x4  __attribute__((ext_vector_type(4)));

__device__ __forceinline__ float gelu_f(float x) {
    return 0.5f * x * (1.0f + erff(x * 0.70710678118654752f));
}
__device__ __forceinline__ ushort f2bf(float x) {       // RNE f32 -> bf16 bits
    uint u = __float_as_uint(x);
    u += 0x7fffu + ((u >> 16) & 1u);
    return (ushort)(u >> 16);
}
__device__ __forceinline__ float bf2f(ushort h) { return __uint_as_float((uint)h << 16); }

// physical LDS ushort offset for (row, chunk) with 2-way-free XOR swizzle
__device__ __forceinline__ int lofs(int row, int chunk) {
    return row * 32 + ((chunk ^ ((row >> 1) & 3)) << 3);
}

// ---------------- weight preconversion ----------------------------------------
// W (Kc x Nc f32, row-major) -> hi/lo bf16 planes transposed [Nc][Kc]
__global__ void prep_w(const float* __restrict__ W, int Kc, int Nc,
                       ushort* __restrict__ hi, ushort* __restrict__ lo) {
    int idx = blockIdx.x * 256 + threadIdx.x;
    if (idx >= Kc * Nc) return;
    int n = idx / Kc, k = idx % Kc;
    float x = W[(long)k * Nc + n];
    ushort h = f2bf(x);
    hi[idx] = h;
    lo[idx] = f2bf(x - bf2f(h));
}
// conv_w (O,I,K) -> [kh][o][i] hi/lo bf16
__global__ void prep_conv(const float* __restrict__ cw,
                          ushort* __restrict__ hi, ushort* __restrict__ lo) {
    int idx = blockIdx.x * 256 + threadIdx.x;
    if (idx >= K_ * C_ * C_) return;
    int kh = idx / (C_ * C_);
    int rem = idx % (C_ * C_);
    int o = rem >> 8, i = rem & 255;
    float x = cw[((long)o * C_ + i) * K_ + kh];
    ushort h = f2bf(x);
    hi[idx] = h;
    lo[idx] = f2bf(x - bf2f(h));
}

// ---------------- bf16x3 MFMA GEMM: Out(M,Nc) = A(M,256f32) @ W(256,Nc) -------
// 128x128 tile, BK=32, 4 waves (2x2), each wave 64x64 = 4x4 mfma 16x16x32 tiles.
__global__ __launch_bounds__(256) void gemm_mfma(
    const float* __restrict__ A, int lda,
    const ushort* __restrict__ Wh, const ushort* __restrict__ Wl, int Kc,
    const float* __restrict__ bias,
    float* __restrict__ Out, int Nc)
{
    __shared__ ushort Ah[128 * 32], Al[128 * 32], Bh[128 * 32], Bl[128 * 32];
    const int tid = threadIdx.x;
    const int row0 = blockIdx.y * 128, col0 = blockIdx.x * 128;
    const int lane = tid & 63;
    const int wid = tid >> 6, wm = wid >> 1, wn = wid & 1;
    const int fr = lane & 15, fc = lane >> 4;
    // staging: 512 16B-units per plane; thread t handles units {t, t+256}
    const int r0 = tid >> 2, c0 = tid & 3;
    const int r1 = (tid + 256) >> 2, c1 = c0;
    const float*  arow0 = A + (long)(row0 + r0) * lda + c0 * 8;
    const float*  arow1 = A + (long)(row0 + r1) * lda + c1 * 8;
    const ushort* wrow0h = Wh + (long)(col0 + r0) * Kc + c0 * 8;
    const ushort* wrow0l = Wl + (long)(col0 + r0) * Kc + c0 * 8;
    const ushort* wrow1h = Wh + (long)(col0 + r1) * Kc + c1 * 8;
    const ushort* wrow1l = Wl + (long)(col0 + r1) * Kc + c1 * 8;
    const int la0 = lofs(r0, c0), la1 = lofs(r1, c1);

    float4 pa0, pa1, pa2, pa3;
    uint4 pw0h, pw0l, pw1h, pw1l;
    #define LOADK(k0) do { \
        pa0 = *(const float4*)(arow0 + (k0));      pa1 = *(const float4*)(arow0 + (k0) + 4); \
        pa2 = *(const float4*)(arow1 + (k0));      pa3 = *(const float4*)(arow1 + (k0) + 4); \
        pw0h = *(const uint4*)(wrow0h + (k0));     pw0l = *(const uint4*)(wrow0l + (k0)); \
        pw1h = *(const uint4*)(wrow1h + (k0));     pw1l = *(const uint4*)(wrow1l + (k0)); \
    } while (0)

    LOADK(0);
    f32x4 acc[4][4] = {};
    for (int k0 = 0; k0 < Kc; k0 += 32) {
        __syncthreads();
        {   // A conversion + store (2 units), W store (2 units x 2 planes)
            float f0[8] = {pa0.x, pa0.y, pa0.z, pa0.w, pa1.x, pa1.y, pa1.z, pa1.w};
            float f1[8] = {pa2.x, pa2.y, pa2.z, pa2.w, pa3.x, pa3.y, pa3.z, pa3.w};
            uint h0[4], l0[4], h1[4], l1[4];
            #pragma unroll
            for (int e = 0; e < 4; ++e) {
                ushort ha = f2bf(f0[2*e]), hb = f2bf(f0[2*e+1]);
                l0[e] = (uint)f2bf(f0[2*e] - bf2f(ha)) | ((uint)f2bf(f0[2*e+1] - bf2f(hb)) << 16);
                h0[e] = (uint)ha | ((uint)hb << 16);
                ushort hc = f2bf(f1[2*e]), hd = f2bf(f1[2*e+1]);
                l1[e] = (uint)f2bf(f1[2*e] - bf2f(hc)) | ((uint)f2bf(f1[2*e+1] - bf2f(hd)) << 16);
                h1[e] = (uint)hc | ((uint)hd << 16);
            }
            *(uint4*)&Ah[la0] = make_uint4(h0[0], h0[1], h0[2], h0[3]);
            *(uint4*)&Al[la0] = make_uint4(l0[0], l0[1], l0[2], l0[3]);
            *(uint4*)&Ah[la1] = make_uint4(h1[0], h1[1], h1[2], h1[3]);
            *(uint4*)&Al[la1] = make_uint4(l1[0], l1[1], l1[2], l1[3]);
            *(uint4*)&Bh[la0] = pw0h;  *(uint4*)&Bl[la0] = pw0l;
            *(uint4*)&Bh[la1] = pw1h;  *(uint4*)&Bl[la1] = pw1l;
        }
        __syncthreads();
        if (k0 + 32 < Kc) LOADK(k0 + 32);
        bf16x8 fah[4], fal[4];
        #pragma unroll
        for (int i = 0; i < 4; ++i) {
            int rA = wm * 64 + i * 16 + fr;
            int oA = lofs(rA, fc);
            fah[i] = *(bf16x8*)&Ah[oA];
            fal[i] = *(bf16x8*)&Al[oA];
        }
        #pragma unroll
        for (int j = 0; j < 4; ++j) {
            int rW = wn * 64 + j * 16 + fr;
            int oW = lofs(rW, fc);
            bf16x8 wh = *(bf16x8*)&Bh[oW];
            bf16x8 wl = *(bf16x8*)&Bl[oW];
            #pragma unroll
            for (int i = 0; i < 4; ++i) {
                acc[i][j] = __builtin_amdgcn_mfma_f32_16x16x32_bf16(fah[i], wh, acc[i][j], 0, 0, 0);
                acc[i][j] = __builtin_amdgcn_mfma_f32_16x16x32_bf16(fah[i], wl, acc[i][j], 0, 0, 0);
                acc[i][j] = __builtin_amdgcn_mfma_f32_16x16x32_bf16(fal[i], wh, acc[i][j], 0, 0, 0);
            }
        }
    }
    #undef LOADK
    float bv[4]; int colv[4];
    #pragma unroll
    for (int j = 0; j < 4; ++j) {
        colv[j] = col0 + wn * 64 + j * 16 + fr;
        bv[j] = bias ? bias[colv[j]] : 0.0f;
    }
    #pragma unroll
    for (int i = 0; i < 4; ++i) {
        long rbase = row0 + wm * 64 + i * 16 + fc * 4;
        #pragma unroll
        for (int r = 0; r < 4; ++r) {
            long ob = (rbase + r) * (long)Nc;
            #pragma unroll
            for (int j = 0; j < 4; ++j)
                Out[ob + colv[j]] = acc[i][j][r] + bv[j];
        }
    }
}

// ---------------- conv(7x1 over T) as bf16x3 MFMA + BN + res + gelu + transpose
__global__ __launch_bounds__(256) void conv_bn_gelu(
    const float* __restrict__ Z,      // (N,T,V,C)
    const ushort* __restrict__ Wh, const ushort* __restrict__ Wl,  // [kh][o][i]
    const float* __restrict__ conv_b, const float* __restrict__ bn_g,
    const float* __restrict__ bn_b,  const float* __restrict__ bn_m,
    const float* __restrict__ bn_v,
    float* __restrict__ Out)          // (N,V,T,C)
{
    __shared__ ushort Ah[128 * 32], Al[128 * 32], Bh[128 * 32], Bl[128 * 32];
    const int tid = threadIdx.x;
    const int row0 = blockIdx.y * 128, col0 = blockIdx.x * 128;
    const int lane = tid & 63;
    const int wid = tid >> 6, wm = wid >> 1, wn = wid & 1;
    const int fr = lane & 15, fc = lane >> 4;
    const int r0 = tid >> 2, c0 = tid & 3;
    const int r1 = (tid + 256) >> 2, c1 = c0;
    const int la0 = lofs(r0, c0), la1 = lofs(r1, c1);
    const int m0 = row0 + r0, m1 = row0 + r1;
    const int t0g = (m0 / V_) % T_, t1g = (m1 / V_) % T_;

    float4 pa0, pa1, pa2, pa3;
    uint4 pw0h, pw0l, pw1h, pw1l;
    auto loadk = [&](int kt) {
        const int kh = kt >> 3, kc = (kt & 7) * 32, d = kh - 3;
        const float z4[4] = {0, 0, 0, 0};
        if (t0g + d >= 0 && t0g + d < T_) {
            const float* zr = Z + (long)(m0 + d * V_) * C_ + kc + c0 * 8;
            pa0 = *(const float4*)zr; pa1 = *(const float4*)(zr + 4);
        } else { pa0 = *(const float4*)z4; pa1 = *(const float4*)z4; }
        if (t1g + d >= 0 && t1g + d < T_) {
            const float* zr = Z + (long)(m1 + d * V_) * C_ + kc + c1 * 8;
            pa2 = *(const float4*)zr; pa3 = *(const float4*)(zr + 4);
        } else { pa2 = *(const float4*)z4; pa3 = *(const float4*)z4; }
        const ushort* w0 = Wh + (long)kh * C_ * C_ + (long)(col0 + r0) * C_ + kc + c0 * 8;
        const ushort* w1 = Wh + (long)kh * C_ * C_ + (long)(col0 + r1) * C_ + kc + c1 * 8;
        const ushort* v0 = Wl + (long)kh * C_ * C_ + (long)(col0 + r0) * C_ + kc + c0 * 8;
        const ushort* v1 = Wl + (long)kh * C_ * C_ + (long)(col0 + r1) * C_ + kc + c1 * 8;
        pw0h = *(const uint4*)w0; pw0l = *(const uint4*)v0;
        pw1h = *(const uint4*)w1; pw1l = *(const uint4*)v1;
    };

    loadk(0);
    f32x4 acc[4][4] = {};
    for (int kt = 0; kt < K_ * 8; ++kt) {     // 56 k-steps of 32
        __syncthreads();
        {
            float f0[8] = {pa0.x, pa0.y, pa0.z, pa0.w, pa1.x, pa1.y, pa1.z, pa1.w};
            float f1[8] = {pa2.x, pa2.y, pa2.z, pa2.w, pa3.x, pa3.y, pa3.z, pa3.w};
            uint h0[4], l0[4], h1[4], l1[4];
            #pragma unroll
            for (int e = 0; e < 4; ++e) {
                ushort ha = f2bf(f0[2*e]), hb = f2bf(f0[2*e+1]);
                l0[e] = (uint)f2bf(f0[2*e] - bf2f(ha)) | ((uint)f2bf(f0[2*e+1] - bf2f(hb)) << 16);
                h0[e] = (uint)ha | ((uint)hb << 16);
                ushort hc = f2bf(f1[2*e]), hd = f2bf(f1[2*e+1]);
                l1[e] = (uint)f2bf(f1[2*e] - bf2f(hc)) | ((uint)f2bf(f1[2*e+1] - bf2f(hd)) << 16);
                h1[e] = (uint)hc | ((uint)hd << 16);
            }
            *(uint4*)&Ah[la0] = make_uint4(h0[0], h0[1], h0[2], h0[3]);
            *(uint4*)&Al[la0] = make_uint4(l0[0], l0[1], l0[2], l0[3]);
            *(uint4*)&Ah[la1] = make_uint4(h1[0], h1[1], h1[2], h1[3]);
            *(uint4*)&Al[la1] = make_uint4(l1[0], l1[1], l1[2], l1[3]);
            *(uint4*)&Bh[la0] = pw0h;  *(uint4*)&Bl[la0] = pw0l;
            *(uint4*)&Bh[la1] = pw1h;  *(uint4*)&Bl[la1] = pw1l;
        }
        __syncthreads();
        if (kt + 1 < K_ * 8) loadk(kt + 1);
        bf16x8 fah[4], fal[4];
        #pragma unroll
        for (int i = 0; i < 4; ++i) {
            int rA = wm * 64 + i * 16 + fr;
            int oA = lofs(rA, fc);
            fah[i] = *(bf16x8*)&Ah[oA];
            fal[i] = *(bf16x8*)&Al[oA];
        }
        #pragma unroll
        for (int j = 0; j < 4; ++j) {
            int rW = wn * 64 + j * 16 + fr;
            int oW = lofs(rW, fc);
            bf16x8 wh = *(bf16x8*)&Bh[oW];
            bf16x8 wl = *(bf16x8*)&Bl[oW];
            #pragma unroll
            for (int i = 0; i < 4; ++i) {
                acc[i][j] = __builtin_amdgcn_mfma_f32_16x16x32_bf16(fah[i], wh, acc[i][j], 0, 0, 0);
                acc[i][j] = __builtin_amdgcn_mfma_f32_16x16x32_bf16(fah[i], wl, acc[i][j], 0, 0, 0);
                acc[i][j] = __builtin_amdgcn_mfma_f32_16x16x32_bf16(fal[i], wh, acc[i][j], 0, 0, 0);
            }
        }
    }
    float cbv[4], scv[4], shv[4]; int colv[4];
    #pragma unroll
    for (int j = 0; j < 4; ++j) {
        int c = col0 + wn * 64 + j * 16 + fr;
        colv[j] = c;
        cbv[j] = conv_b[c];
        float sc = rsqrtf(bn_v[c] + 1e-5f) * bn_g[c];
        scv[j] = sc;
        shv[j] = bn_b[c] - bn_m[c] * sc;
    }
    #pragma unroll
    for (int i = 0; i < 4; ++i)
        #pragma unroll
        for (int r = 0; r < 4; ++r) {
            int m = row0 + wm * 64 + i * 16 + fc * 4 + r;
            int n = m / (T_ * V_);
            int rem = m % (T_ * V_);
            int t = rem / V_, v = rem % V_;
            long ob = (((long)n * V_ + v) * T_ + t) * C_;
            long zb = (long)m * C_;
            #pragma unroll
            for (int j = 0; j < 4; ++j) {
                float cv = acc[i][j][r] + cbv[j];
                float bn = cv * scv[j] + shv[j];
                Out[ob + colv[j]] = gelu_f(Z[zb + colv[j]] + bn);
            }
        }
}

// ---------------- small utility kernels ---------------------------------------
__global__ void zero_f32(float* __restrict__ p, int n) {
    int i = blockIdx.x * 256 + threadIdx.x;
    if (i < n) p[i] = 0.0f;
}

// ---------------- spatial attention scores ------------------------------------
__global__ __launch_bounds__(256) void att_s_partial(
    const float* __restrict__ QK,     // (N,V,T,384)
    float* __restrict__ attPre)       // (N,V,V,S) zero-init
{
    const int n = blockIdx.x;
    const int tg = blockIdx.y;        // 0..7, 8 t's each
    __shared__ float lds[V_ * 384];   // 9600 floats
    const int NOUT = V_ * V_ * S_;    // 1875
    float acc[8] = {};
    for (int ttc = 0; ttc < 8; ++ttc) {
        int t = tg * 8 + ttc;
        __syncthreads();
        for (int l = threadIdx.x; l < V_ * 384; l += 256) {
            int v = l / 384, j = l % 384;
            lds[l] = QK[(((long)n * V_ + v) * T_ + t) * 384 + j];
        }
        __syncthreads();
        int ai = 0;
        for (int o = threadIdx.x; o < NOUT; o += 256, ++ai) {
            int u = o / (V_ * S_), rem = o % (V_ * S_), v = rem / S_, s = rem % S_;
            const float* qp = &lds[u * 384 + s];
            const float* kp = &lds[v * 384 + S_ + s];
            float sum = 0.f;
            #pragma unroll 8
            for (int ci = 0; ci < CI_; ++ci) sum += qp[ci * 6] * kp[ci * 6];
            acc[ai] += sum;
        }
    }
    int ai = 0;
    for (int o = threadIdx.x; o < NOUT; o += 256, ++ai)
        atomicAdd(&attPre[(long)n * NOUT + o], acc[ai]);
}

__global__ void att_s_final(const float* __restrict__ attPre,
                            const float* __restrict__ alphas,
                            const float* __restrict__ att0,
                            float* __restrict__ attS) {
    int idx = blockIdx.x * 256 + threadIdx.x;
    if (idx >= N_ * V_ * V_ * S_) return;
    int o = idx % (V_ * V_ * S_);
    int s = o % S_;
    attS[idx] = tanhf(attPre[idx] * (1.0f / (CI_ * T_))) * alphas[s] + att0[o];
}

// ---------------- fused spatial mixing ----------------------------------------
__global__ __launch_bounds__(256) void vmix_all(
    const float* __restrict__ G,      // (M, 768)
    const float* __restrict__ attS,   // (N,V,V,S)
    const float* __restrict__ bias,   // (C)
    float* __restrict__ P)            // (N,V,TC)
{
    const int n = blockIdx.y;
    const int t = blockIdx.x;         // 0..63
    const int c = threadIdx.x;        // 0..255
    __shared__ float a[3][V_ * V_];
    for (int l = threadIdx.x; l < V_ * V_ * S_; l += 256) {
        int uv = l / S_, s = l % S_;
        a[s][uv] = attS[((long)n * V_ * V_ + uv) * S_ + s];
    }
    __syncthreads();
    float acc[V_] = {};
    for (int u = 0; u < V_; ++u) {
        const float* g = G + ((long)((n * V_ + u) * T_) + t) * 768 + c;
        float v0 = g[0], v1 = g[256], v2 = g[512];
        const float* a0 = &a[0][u * V_], *a1 = &a[1][u * V_], *a2 = &a[2][u * V_];
        #pragma unroll
        for (int v = 0; v < V_; ++v)
            acc[v] += a0[v] * v0 + a1[v] * v1 + a2[v] * v2;
    }
    const float b = bias[c];
    for (int v = 0; v < V_; ++v)
        P[((long)(n * V_ + v) * T_ + t) * C_ + c] = acc[v] + b;
}

// ---------------- temporal attention scores -----------------------------------
__global__ __launch_bounds__(256) void att_t(
    const float* __restrict__ QKT,    // (N,T,V,512)
    const float* __restrict__ alphat_f, const float* __restrict__ alphat_b,
    float* __restrict__ attF, float* __restrict__ attB)   // (N,2,T,T) [t][q]
{
    const int n = blockIdx.z;
    const int t0 = blockIdx.y * 16, q0 = blockIdx.x * 16;
    __shared__ float Qs[16 * 256], Ks[16 * 256];
    const int tt = threadIdx.x / 16, qq = threadIdx.x % 16;
    float acc[4] = {};
    for (int v = 0; v < V_; ++v) {
        for (int h = 0; h < 2; ++h) {
            __syncthreads();
            for (int l = threadIdx.x; l < 16 * 256; l += 256) {
                int r = l >> 8, c = l & 255;
                Qs[l] = QKT[(((long)n * T_ + t0 + r) * V_ + v) * 512 + h * 256 + c];
                Ks[l] = QKT[(((long)n * T_ + q0 + r) * V_ + v) * 512 + h * 256 + c];
            }
            __syncthreads();
            #pragma unroll 8
            for (int ci = 0; ci < 32; ++ci) {
                const float* qp = &Qs[tt * 256 + ci * 8];
                const float* kp = &Ks[qq * 256 + ci * 8];
                acc[0] += qp[0] * kp[4];
                acc[1] += qp[1] * kp[5];
                acc[2] += qp[2] * kp[6];
                acc[3] += qp[3] * kp[7];
            }
        }
    }
    const int t = t0 + tt, q = q0 + qq;
    const float mf = (t >= q) ? 1.0f : 0.0f;   // bmask.T
    const float mb = (q >= t) ? 1.0f : 0.0f;   // bmask
    const float inv = 1.0f / (CI_ * V_);
    for (int s = 0; s < 2; ++s) {
        attF[(((long)n * 2 + s) * T_ + t) * T_ + q] = tanhf(acc[s]     * inv) * alphat_f[s] * mf;
        attB[(((long)n * 2 + s) * T_ + t) * T_ + q] = tanhf(acc[2 + s] * inv) * alphat_b[s] * mb;
    }
}

// ---------------- fused temporal mixing ---------------------------------------
template <bool INIT>
__global__ __launch_bounds__(256) void tmix_all(
    const float* __restrict__ G,      // (M, 512) rows (n*T+t)*V+v
    const float* __restrict__ att,    // (N,2,T,T)
    const float* __restrict__ bias,   // (C) or null
    float* __restrict__ P)            // (N,T,VC)
{
    const int n = blockIdx.y;
    const int col = blockIdx.x * 64 + (threadIdx.x & 63);  // 0..VC-1
    const int ty = threadIdx.x >> 6;                       // 0..3
    const int v = col >> 8, c = col & 255;
    __shared__ float a[2 * T_ * T_];
    for (int l = threadIdx.x; l < 2 * T_ * T_; l += 256)
        a[l] = att[(long)n * 2 * T_ * T_ + l];
    __syncthreads();
    float acc[16] = {};
    for (int t = 0; t < T_; ++t) {
        const float* g = G + ((long)((n * T_ + t) * V_) + v) * 512 + c;
        float v0 = g[0], v1 = g[256];
        const float* ar0 = &a[t * T_ + ty * 16];
        const float* ar1 = ar0 + T_ * T_;
        #pragma unroll
        for (int i = 0; i < 16; ++i) acc[i] += ar0[i] * v0 + ar1[i] * v1;
    }
    for (int i = 0; i < 16; ++i) {
        int q = ty * 16 + i;
        long idx = ((long)n * T_ + q) * VC_ + col;
        if (INIT) P[idx] = acc[i] + bias[c];
        else      P[idx] += acc[i];
    }
}

// ---------------- LayerNorm over (T,C) per (n,v) ------------------------------
template <bool TR>
__global__ __launch_bounds__(256) void ln_res_gelu_TC(
    const float* __restrict__ P, const float* __restrict__ X,
    const float* __restrict__ G, const float* __restrict__ B,
    float* __restrict__ Out)
{
    const int g = blockIdx.x;          // n*V+v
    const int n = g / V_, v = g % V_;
    const float* p = P + (long)g * TC_;
    const float* x = X + (long)g * TC_;
    float s = 0.f, ss = 0.f;
    for (int i = threadIdx.x; i < TC_; i += 256) { float a = p[i]; s += a; ss += a * a; }
    __shared__ float rs[4], rss[4];
    #pragma unroll
    for (int off = 32; off > 0; off >>= 1) { s += __shfl_down(s, off); ss += __shfl_down(ss, off); }
    if ((threadIdx.x & 63) == 0) { rs[threadIdx.x >> 6] = s; rss[threadIdx.x >> 6] = ss; }
    __syncthreads();
    s = rs[0] + rs[1] + rs[2] + rs[3];
    ss = rss[0] + rss[1] + rss[2] + rss[3];
    const float mean = s * (1.0f / TC_);
    const float var  = ss * (1.0f / TC_) - mean * mean;
    const float rstd = rsqrtf(var + 1e-5f);
    for (int i = threadIdx.x; i < TC_; i += 256) {
        float val = (p[i] - mean) * rstd * G[i] + B[i];
        float r = gelu_f(x[i] + val);
        if (TR) {
            int t = i >> 8, c = i & 255;
            Out[(((long)n * T_ + t) * V_ + v) * C_ + c] = r;   // write (N,T,V,C)
        } else {
            Out[(long)g * TC_ + i] = r;
        }
    }
}

// ---------------- LayerNorm over (V,C) per (n,t) ------------------------------
__global__ __launch_bounds__(256) void ln_res_gelu_VC(
    const float* __restrict__ P, const float* __restrict__ X,
    const float* __restrict__ G, const float* __restrict__ B,
    float* __restrict__ Out)
{
    const int g = blockIdx.x;          // n*T+t
    const float* p = P + (long)g * VC_;
    const float* x = X + (long)g * VC_;
    float s = 0.f, ss = 0.f;
    for (int i = threadIdx.x; i < VC_; i += 256) { float a = p[i]; s += a; ss += a * a; }
    __shared__ float rs[4], rss[4];
    #pragma unroll
    for (int off = 32; off > 0; off >>= 1) { s += __shfl_down(s, off); ss += __shfl_down(ss, off); }
    if ((threadIdx.x & 63) == 0) { rs[threadIdx.x >> 6] = s; rss[threadIdx.x >> 6] = ss; }
    __syncthreads();
    s = rs[0] + rs[1] + rs[2] + rs[3];
    ss = rss[0] + rss[1] + rss[2] + rss[3];
    const float mean = s * (1.0f / VC_);
    const float var  = ss * (1.0f / VC_) - mean * mean;
    const float rstd = rsqrtf(var + 1e-5f);
    for (int i = threadIdx.x; i < VC_; i += 256) {
        float val = (p[i] - mean) * rstd * G[i] + B[i];
        Out[(long)g * VC_ + i] = gelu_f(x[i] + val);
    }
}

// ==============================================================================
extern "C" void kernel_launch(void* const* d_in, const int* in_sizes, int n_in,
                              void* d_out, int out_size, void* d_ws, size_t ws_size,
                              hipStream_t stream)
{
    const float* x        = (const float*)d_in[0];
    const float* Wqk_s    = (const float*)d_in[1];
    const float* bqk_s    = (const float*)d_in[2];
    const float* alphas   = (const float*)d_in[3];
    const float* att0s    = (const float*)d_in[4];
    const float* Wo_s     = (const float*)d_in[5];
    const float* bo_s     = (const float*)d_in[6];
    const float* g_os     = (const float*)d_in[7];
    const float* b_os     = (const float*)d_in[8];
    const float* Wff_s    = (const float*)d_in[9];
    const float* bff_s    = (const float*)d_in[10];
    const float* g_ffs    = (const float*)d_in[11];
    const float* b_ffs    = (const float*)d_in[12];
    const float* Wqk_t    = (const float*)d_in[13];
    const float* bqk_t    = (const float*)d_in[14];
    const float* alphat_f = (const float*)d_in[15];
    const float* alphat_b = (const float*)d_in[16];
    const float* Wo_t     = (const float*)d_in[17];
    const float* bo_t     = (const float*)d_in[18];
    const float* g_ot     = (const float*)d_in[19];
    const float* b_ot     = (const float*)d_in[20];
    const float* Wff_t    = (const float*)d_in[21];
    const float* bff_t    = (const float*)d_in[22];
    const float* g_fft    = (const float*)d_in[23];
    const float* b_fft    = (const float*)d_in[24];
    const float* conv_w   = (const float*)d_in[25];
    const float* conv_b   = (const float*)d_in[26];
    const float* bn_g     = (const float*)d_in[27];
    const float* bn_b     = (const float*)d_in[28];
    const float* bn_m     = (const float*)d_in[29];
    const float* bn_v     = (const float*)d_in[30];

    float* B  = (float*)d_ws;
    float* B0  = B;
    float* B13 = B + TOT_;            // +13.1M
    float* B26 = B + 2 * TOT_;        // +26.2M
    float* B39 = B + 3 * TOT_;        // +39.3M
    float* RA  = B + 4 * TOT_;        // +52.4M small buffers
    float* attPre = RA;                               // 60,000
    float* attS   = attPre + N_*V_*V_*S_;             // 60,000
    float* attF   = attS   + N_*V_*V_*S_;             // 262,144
    float* attB   = attF   + (long)N_*2*T_*T_;        // 262,144
    // bf16 weight planes (ushort), after attB
    ushort* wp = (ushort*)(attB + (long)N_*2*T_*T_);
    ushort* qs_h = wp;  wp += 384*256;   ushort* qs_l = wp;  wp += 384*256;
    ushort* os_h = wp;  wp += 768*256;   ushort* os_l = wp;  wp += 768*256;
    ushort* fs_h = wp;  wp += 256*256;   ushort* fs_l = wp;  wp += 256*256;
    ushort* qt_h = wp;  wp += 512*256;   ushort* qt_l = wp;  wp += 512*256;
    ushort* ot0_h= wp;  wp += 512*256;   ushort* ot0_l= wp;  wp += 512*256;
    ushort* ot1_h= wp;  wp += 512*256;   ushort* ot1_l= wp;  wp += 512*256;
    ushort* ft_h = wp;  wp += 256*256;   ushort* ft_l = wp;  wp += 256*256;
    ushort* cv_h = wp;  wp += K_*256*256; ushort* cv_l = wp;
    float* YT = (float*)d_out;        // y^T (N,T,V,C); overwritten at the end

    // ---- weight preconversion (hi/lo bf16, transposed [N][K]) ----
    auto prepw = [&](const float* W, int Kc, int Nc, ushort* h, ushort* l) {
        prep_w<<<(Kc*Nc + 255)/256, 256, 0, stream>>>(W, Kc, Nc, h, l);
    };
    prepw(Wqk_s, C_, 384, qs_h, qs_l);
    prepw(Wo_s,  C_, 768, os_h, os_l);
    prepw(Wff_s, C_, 256, fs_h, fs_l);
    prepw(Wqk_t, C_, 512, qt_h, qt_l);
    prepw(Wo_t,                      C_, 512, ot0_h, ot0_l);
    prepw(Wo_t + (long)ST_*C_*C_,    C_, 512, ot1_h, ot1_l);
    prepw(Wff_t, C_, 256, ft_h, ft_l);
    prep_conv<<<(K_*C_*C_ + 255)/256, 256, 0, stream>>>(conv_w, cv_h, cv_l);

    // ---- Stage 1: spatial ----
    gemm_mfma<<<dim3(384/128, M_/128), 256, 0, stream>>>(x, C_, qs_h, qs_l, C_, bqk_s, B0, 384);
    zero_f32<<<(N_*V_*V_*S_ + 255)/256, 256, 0, stream>>>(attPre, N_*V_*V_*S_);
    att_s_partial<<<dim3(N_, 8), 256, 0, stream>>>(B0, attPre);
    att_s_final<<<(N_*V_*V_*S_ + 255)/256, 256, 0, stream>>>(attPre, alphas, att0s, attS);
    gemm_mfma<<<dim3(768/128, M_/128), 256, 0, stream>>>(x, C_, os_h, os_l, C_, nullptr, B0, 768);
    vmix_all<<<dim3(T_, N_), 256, 0, stream>>>(B0, attS, bo_s, B39);
    ln_res_gelu_TC<false><<<N_*V_, 256, 0, stream>>>(B39, x, g_os, b_os, B0);
    gemm_mfma<<<dim3(256/128, M_/128), 256, 0, stream>>>(B0, C_, fs_h, fs_l, C_, bff_s, B13, 256);
    ln_res_gelu_TC<true><<<N_*V_, 256, 0, stream>>>(B13, x, g_ffs, b_ffs, YT);

    // ---- Stage 2: temporal ----
    gemm_mfma<<<dim3(512/128, M_/128), 256, 0, stream>>>(YT, C_, qt_h, qt_l, C_, bqk_t, B0, 512);
    att_t<<<dim3(4, 4, N_), 256, 0, stream>>>(B0, alphat_f, alphat_b, attF, attB);
    gemm_mfma<<<dim3(512/128, M_/128), 256, 0, stream>>>(YT, C_, ot0_h, ot0_l, C_, nullptr, B26, 512);
    tmix_all<true><<<dim3(VC_/64, N_), 256, 0, stream>>>(B26, attF, bo_t, B0);
    gemm_mfma<<<dim3(512/128, M_/128), 256, 0, stream>>>(YT, C_, ot1_h, ot1_l, C_, nullptr, B26, 512);
    tmix_all<false><<<dim3(VC_/64, N_), 256, 0, stream>>>(B26, attB, nullptr, B0);
    ln_res_gelu_VC<<<N_*T_, 256, 0, stream>>>(B0, YT, g_ot, b_ot, B13);
    gemm_mfma<<<dim3(256/128, M_/128), 256, 0, stream>>>(B13, C_, ft_h, ft_l, C_, bff_t, B26, 256);
    ln_res_gelu_VC<<<N_*T_, 256, 0, stream>>>(B26, YT, g_fft, b_fft, B39);

    // ---- Stage 3: conv + BN + gelu + transpose ----
    conv_bn_gelu<<<dim3(C_/128, M_/128), 256, 0, stream>>>(B39, cv_h, cv_l, conv_b, bn_g, bn_b, bn_m, bn_v, (float*)d_out);
}

// Round 4
// 1480.306 us; speedup vs baseline: 3.0261x; 1.3070x over previous
//
#include <hip/hip_runtime.h>

static constexpr int N_ = 32, V_ = 25, T_ = 64, C_ = 256;
static constexpr int S_ = 3, ST_ = 2, CI_ = 64, K_ = 7;
static constexpr int M_  = N_ * V_ * T_;          // 51200 rows (also N*T*V)
static constexpr int TC_ = T_ * C_;               // 16384
static constexpr int VC_ = V_ * C_;               // 6400
static constexpr long TOT_ = (long)M_ * C_;       // 13,107,200
static constexpr long PLANE_ = 2048L * 1600;      // per-chan QKT plane (ushorts)

typedef __bf16 bf16x8 __attribute__((ext_vector_type(8)));
typedef float  f32x4  __attribute__((ext_vector_type(4)));

__device__ __forceinline__ float gelu_f(float x) {
    return 0.5f * x * (1.0f + erff(x * 0.70710678118654752f));
}
__device__ __forceinline__ ushort f2bf(float x) {       // RNE f32 -> bf16 bits
    uint u = __float_as_uint(x);
    u += 0x7fffu + ((u >> 16) & 1u);
    return (ushort)(u >> 16);
}
__device__ __forceinline__ float bf2f(ushort h) { return __uint_as_float((uint)h << 16); }

// physical LDS ushort offset for (row, chunk) with 2-way-free XOR swizzle
__device__ __forceinline__ int lofs(int row, int chunk) {
    return row * 32 + ((chunk ^ ((row >> 1) & 3)) << 3);
}

// ---------------- weight preconversion ----------------------------------------
__global__ void prep_w(const float* __restrict__ W, int Kc, int Nc,
                       ushort* __restrict__ hi, ushort* __restrict__ lo) {
    int idx = blockIdx.x * 256 + threadIdx.x;
    if (idx >= Kc * Nc) return;
    int n = idx / Kc, k = idx % Kc;
    float x = W[(long)k * Nc + n];
    ushort h = f2bf(x);
    hi[idx] = h;
    lo[idx] = f2bf(x - bf2f(h));
}
__global__ void prep_conv(const float* __restrict__ cw,
                          ushort* __restrict__ hi, ushort* __restrict__ lo) {
    int idx = blockIdx.x * 256 + threadIdx.x;
    if (idx >= K_ * C_ * C_) return;
    int kh = idx / (C_ * C_);
    int rem = idx % (C_ * C_);
    int o = rem >> 8, i = rem & 255;
    float x = cw[((long)o * C_ + i) * K_ + kh];
    ushort h = f2bf(x);
    hi[idx] = h;
    lo[idx] = f2bf(x - bf2f(h));
}

// ---------------- bf16x3 MFMA GEMM: Out(M,Nc) = A(M,256f32) @ W(256,Nc) -------
__global__ __launch_bounds__(256) void gemm_mfma(
    const float* __restrict__ A, int lda,
    const ushort* __restrict__ Wh, const ushort* __restrict__ Wl, int Kc,
    const float* __restrict__ bias,
    float* __restrict__ Out, int Nc)
{
    __shared__ ushort Ah[128 * 32], Al[128 * 32], Bh[128 * 32], Bl[128 * 32];
    const int tid = threadIdx.x;
    const int row0 = blockIdx.y * 128, col0 = blockIdx.x * 128;
    const int lane = tid & 63;
    const int wid = tid >> 6, wm = wid >> 1, wn = wid & 1;
    const int fr = lane & 15, fc = lane >> 4;
    const int r0 = tid >> 2, c0 = tid & 3;
    const int r1 = (tid + 256) >> 2, c1 = c0;
    const float*  arow0 = A + (long)(row0 + r0) * lda + c0 * 8;
    const float*  arow1 = A + (long)(row0 + r1) * lda + c1 * 8;
    const ushort* wrow0h = Wh + (long)(col0 + r0) * Kc + c0 * 8;
    const ushort* wrow0l = Wl + (long)(col0 + r0) * Kc + c0 * 8;
    const ushort* wrow1h = Wh + (long)(col0 + r1) * Kc + c1 * 8;
    const ushort* wrow1l = Wl + (long)(col0 + r1) * Kc + c1 * 8;
    const int la0 = lofs(r0, c0), la1 = lofs(r1, c1);

    float4 pa0, pa1, pa2, pa3;
    uint4 pw0h, pw0l, pw1h, pw1l;
    #define LOADK(k0) do { \
        pa0 = *(const float4*)(arow0 + (k0));      pa1 = *(const float4*)(arow0 + (k0) + 4); \
        pa2 = *(const float4*)(arow1 + (k0));      pa3 = *(const float4*)(arow1 + (k0) + 4); \
        pw0h = *(const uint4*)(wrow0h + (k0));     pw0l = *(const uint4*)(wrow0l + (k0)); \
        pw1h = *(const uint4*)(wrow1h + (k0));     pw1l = *(const uint4*)(wrow1l + (k0)); \
    } while (0)

    LOADK(0);
    f32x4 acc[4][4] = {};
    for (int k0 = 0; k0 < Kc; k0 += 32) {
        __syncthreads();
        {
            float f0[8] = {pa0.x, pa0.y, pa0.z, pa0.w, pa1.x, pa1.y, pa1.z, pa1.w};
            float f1[8] = {pa2.x, pa2.y, pa2.z, pa2.w, pa3.x, pa3.y, pa3.z, pa3.w};
            uint h0[4], l0[4], h1[4], l1[4];
            #pragma unroll
            for (int e = 0; e < 4; ++e) {
                ushort ha = f2bf(f0[2*e]), hb = f2bf(f0[2*e+1]);
                l0[e] = (uint)f2bf(f0[2*e] - bf2f(ha)) | ((uint)f2bf(f0[2*e+1] - bf2f(hb)) << 16);
                h0[e] = (uint)ha | ((uint)hb << 16);
                ushort hc = f2bf(f1[2*e]), hd = f2bf(f1[2*e+1]);
                l1[e] = (uint)f2bf(f1[2*e] - bf2f(hc)) | ((uint)f2bf(f1[2*e+1] - bf2f(hd)) << 16);
                h1[e] = (uint)hc | ((uint)hd << 16);
            }
            *(uint4*)&Ah[la0] = make_uint4(h0[0], h0[1], h0[2], h0[3]);
            *(uint4*)&Al[la0] = make_uint4(l0[0], l0[1], l0[2], l0[3]);
            *(uint4*)&Ah[la1] = make_uint4(h1[0], h1[1], h1[2], h1[3]);
            *(uint4*)&Al[la1] = make_uint4(l1[0], l1[1], l1[2], l1[3]);
            *(uint4*)&Bh[la0] = pw0h;  *(uint4*)&Bl[la0] = pw0l;
            *(uint4*)&Bh[la1] = pw1h;  *(uint4*)&Bl[la1] = pw1l;
        }
        __syncthreads();
        if (k0 + 32 < Kc) LOADK(k0 + 32);
        bf16x8 fah[4], fal[4];
        #pragma unroll
        for (int i = 0; i < 4; ++i) {
            int rA = wm * 64 + i * 16 + fr;
            int oA = lofs(rA, fc);
            fah[i] = *(bf16x8*)&Ah[oA];
            fal[i] = *(bf16x8*)&Al[oA];
        }
        #pragma unroll
        for (int j = 0; j < 4; ++j) {
            int rW = wn * 64 + j * 16 + fr;
            int oW = lofs(rW, fc);
            bf16x8 wh = *(bf16x8*)&Bh[oW];
            bf16x8 wl = *(bf16x8*)&Bl[oW];
            #pragma unroll
            for (int i = 0; i < 4; ++i) {
                acc[i][j] = __builtin_amdgcn_mfma_f32_16x16x32_bf16(fah[i], wh, acc[i][j], 0, 0, 0);
                acc[i][j] = __builtin_amdgcn_mfma_f32_16x16x32_bf16(fah[i], wl, acc[i][j], 0, 0, 0);
                acc[i][j] = __builtin_amdgcn_mfma_f32_16x16x32_bf16(fal[i], wh, acc[i][j], 0, 0, 0);
            }
        }
    }
    #undef LOADK
    float bv[4]; int colv[4];
    #pragma unroll
    for (int j = 0; j < 4; ++j) {
        colv[j] = col0 + wn * 64 + j * 16 + fr;
        bv[j] = bias ? bias[colv[j]] : 0.0f;
    }
    #pragma unroll
    for (int i = 0; i < 4; ++i) {
        long rbase = row0 + wm * 64 + i * 16 + fc * 4;
        #pragma unroll
        for (int r = 0; r < 4; ++r) {
            long ob = (rbase + r) * (long)Nc;
            #pragma unroll
            for (int j = 0; j < 4; ++j)
                Out[ob + colv[j]] = acc[i][j][r] + bv[j];
        }
    }
}

// ---------------- conv(7x1 over T) as bf16x3 MFMA + BN + res + gelu + transpose
__global__ __launch_bounds__(256) void conv_bn_gelu(
    const float* __restrict__ Z,      // (N,T,V,C)
    const ushort* __restrict__ Wh, const ushort* __restrict__ Wl,  // [kh][o][i]
    const float* __restrict__ conv_b, const float* __restrict__ bn_g,
    const float* __restrict__ bn_b,  const float* __restrict__ bn_m,
    const float* __restrict__ bn_v,
    float* __restrict__ Out)          // (N,V,T,C)
{
    __shared__ ushort Ah[128 * 32], Al[128 * 32], Bh[128 * 32], Bl[128 * 32];
    const int tid = threadIdx.x;
    const int row0 = blockIdx.y * 128, col0 = blockIdx.x * 128;
    const int lane = tid & 63;
    const int wid = tid >> 6, wm = wid >> 1, wn = wid & 1;
    const int fr = lane & 15, fc = lane >> 4;
    const int r0 = tid >> 2, c0 = tid & 3;
    const int r1 = (tid + 256) >> 2, c1 = c0;
    const int la0 = lofs(r0, c0), la1 = lofs(r1, c1);
    const int m0 = row0 + r0, m1 = row0 + r1;
    const int t0g = (m0 / V_) % T_, t1g = (m1 / V_) % T_;

    float4 pa0, pa1, pa2, pa3;
    uint4 pw0h, pw0l, pw1h, pw1l;
    auto loadk = [&](int kt) {
        const int kh = kt >> 3, kc = (kt & 7) * 32, d = kh - 3;
        const float z4[4] = {0, 0, 0, 0};
        if (t0g + d >= 0 && t0g + d < T_) {
            const float* zr = Z + (long)(m0 + d * V_) * C_ + kc + c0 * 8;
            pa0 = *(const float4*)zr; pa1 = *(const float4*)(zr + 4);
        } else { pa0 = *(const float4*)z4; pa1 = *(const float4*)z4; }
        if (t1g + d >= 0 && t1g + d < T_) {
            const float* zr = Z + (long)(m1 + d * V_) * C_ + kc + c1 * 8;
            pa2 = *(const float4*)zr; pa3 = *(const float4*)(zr + 4);
        } else { pa2 = *(const float4*)z4; pa3 = *(const float4*)z4; }
        const ushort* w0 = Wh + (long)kh * C_ * C_ + (long)(col0 + r0) * C_ + kc + c0 * 8;
        const ushort* w1 = Wh + (long)kh * C_ * C_ + (long)(col0 + r1) * C_ + kc + c1 * 8;
        const ushort* v0 = Wl + (long)kh * C_ * C_ + (long)(col0 + r0) * C_ + kc + c0 * 8;
        const ushort* v1 = Wl + (long)kh * C_ * C_ + (long)(col0 + r1) * C_ + kc + c1 * 8;
        pw0h = *(const uint4*)w0; pw0l = *(const uint4*)v0;
        pw1h = *(const uint4*)w1; pw1l = *(const uint4*)v1;
    };

    loadk(0);
    f32x4 acc[4][4] = {};
    for (int kt = 0; kt < K_ * 8; ++kt) {     // 56 k-steps of 32
        __syncthreads();
        {
            float f0[8] = {pa0.x, pa0.y, pa0.z, pa0.w, pa1.x, pa1.y, pa1.z, pa1.w};
            float f1[8] = {pa2.x, pa2.y, pa2.z, pa2.w, pa3.x, pa3.y, pa3.z, pa3.w};
            uint h0[4], l0[4], h1[4], l1[4];
            #pragma unroll
            for (int e = 0; e < 4; ++e) {
                ushort ha = f2bf(f0[2*e]), hb = f2bf(f0[2*e+1]);
                l0[e] = (uint)f2bf(f0[2*e] - bf2f(ha)) | ((uint)f2bf(f0[2*e+1] - bf2f(hb)) << 16);
                h0[e] = (uint)ha | ((uint)hb << 16);
                ushort hc = f2bf(f1[2*e]), hd = f2bf(f1[2*e+1]);
                l1[e] = (uint)f2bf(f1[2*e] - bf2f(hc)) | ((uint)f2bf(f1[2*e+1] - bf2f(hd)) << 16);
                h1[e] = (uint)hc | ((uint)hd << 16);
            }
            *(uint4*)&Ah[la0] = make_uint4(h0[0], h0[1], h0[2], h0[3]);
            *(uint4*)&Al[la0] = make_uint4(l0[0], l0[1], l0[2], l0[3]);
            *(uint4*)&Ah[la1] = make_uint4(h1[0], h1[1], h1[2], h1[3]);
            *(uint4*)&Al[la1] = make_uint4(l1[0], l1[1], l1[2], l1[3]);
            *(uint4*)&Bh[la0] = pw0h;  *(uint4*)&Bl[la0] = pw0l;
            *(uint4*)&Bh[la1] = pw1h;  *(uint4*)&Bl[la1] = pw1l;
        }
        __syncthreads();
        if (kt + 1 < K_ * 8) loadk(kt + 1);
        bf16x8 fah[4], fal[4];
        #pragma unroll
        for (int i = 0; i < 4; ++i) {
            int rA = wm * 64 + i * 16 + fr;
            int oA = lofs(rA, fc);
            fah[i] = *(bf16x8*)&Ah[oA];
            fal[i] = *(bf16x8*)&Al[oA];
        }
        #pragma unroll
        for (int j = 0; j < 4; ++j) {
            int rW = wn * 64 + j * 16 + fr;
            int oW = lofs(rW, fc);
            bf16x8 wh = *(bf16x8*)&Bh[oW];
            bf16x8 wl = *(bf16x8*)&Bl[oW];
            #pragma unroll
            for (int i = 0; i < 4; ++i) {
                acc[i][j] = __builtin_amdgcn_mfma_f32_16x16x32_bf16(fah[i], wh, acc[i][j], 0, 0, 0);
                acc[i][j] = __builtin_amdgcn_mfma_f32_16x16x32_bf16(fah[i], wl, acc[i][j], 0, 0, 0);
                acc[i][j] = __builtin_amdgcn_mfma_f32_16x16x32_bf16(fal[i], wh, acc[i][j], 0, 0, 0);
            }
        }
    }
    float cbv[4], scv[4], shv[4]; int colv[4];
    #pragma unroll
    for (int j = 0; j < 4; ++j) {
        int c = col0 + wn * 64 + j * 16 + fr;
        colv[j] = c;
        cbv[j] = conv_b[c];
        float sc = rsqrtf(bn_v[c] + 1e-5f) * bn_g[c];
        scv[j] = sc;
        shv[j] = bn_b[c] - bn_m[c] * sc;
    }
    #pragma unroll
    for (int i = 0; i < 4; ++i)
        #pragma unroll
        for (int r = 0; r < 4; ++r) {
            int m = row0 + wm * 64 + i * 16 + fc * 4 + r;
            int n = m / (T_ * V_);
            int rem = m % (T_ * V_);
            int t = rem / V_, v = rem % V_;
            long ob = (((long)n * V_ + v) * T_ + t) * C_;
            long zb = (long)m * C_;
            #pragma unroll
            for (int j = 0; j < 4; ++j) {
                float cv = acc[i][j][r] + cbv[j];
                float bn = cv * scv[j] + shv[j];
                Out[ob + colv[j]] = gelu_f(Z[zb + colv[j]] + bn);
            }
        }
}

// ---------------- small utility kernels ---------------------------------------
__global__ void zero_f32(float* __restrict__ p, int n) {
    int i = blockIdx.x * 256 + threadIdx.x;
    if (i < n) p[i] = 0.0f;
}

// ---------------- spatial attention scores ------------------------------------
__global__ __launch_bounds__(256) void att_s_partial(
    const float* __restrict__ QK,     // (N,V,T,384)
    float* __restrict__ attPre)       // (N,V,V,S) zero-init
{
    const int n = blockIdx.x;
    const int tg = blockIdx.y;        // 0..7, 8 t's each
    __shared__ float lds[V_ * 384];   // 9600 floats
    const int NOUT = V_ * V_ * S_;    // 1875
    float acc[8] = {};
    for (int ttc = 0; ttc < 8; ++ttc) {
        int t = tg * 8 + ttc;
        __syncthreads();
        for (int l = threadIdx.x; l < V_ * 384; l += 256) {
            int v = l / 384, j = l % 384;
            lds[l] = QK[(((long)n * V_ + v) * T_ + t) * 384 + j];
        }
        __syncthreads();
        int ai = 0;
        for (int o = threadIdx.x; o < NOUT; o += 256, ++ai) {
            int u = o / (V_ * S_), rem = o % (V_ * S_), v = rem / S_, s = rem % S_;
            const float* qp = &lds[u * 384 + s];
            const float* kp = &lds[v * 384 + S_ + s];
            float sum = 0.f;
            #pragma unroll 8
            for (int ci = 0; ci < CI_; ++ci) sum += qp[ci * 6] * kp[ci * 6];
            acc[ai] += sum;
        }
    }
    int ai = 0;
    for (int o = threadIdx.x; o < NOUT; o += 256, ++ai)
        atomicAdd(&attPre[(long)n * NOUT + o], acc[ai]);
}

__global__ void att_s_final(const float* __restrict__ attPre,
                            const float* __restrict__ alphas,
                            const float* __restrict__ att0,
                            float* __restrict__ attS) {
    int idx = blockIdx.x * 256 + threadIdx.x;
    if (idx >= N_ * V_ * V_ * S_) return;
    int o = idx % (V_ * V_ * S_);
    int s = o % S_;
    attS[idx] = tanhf(attPre[idx] * (1.0f / (CI_ * T_))) * alphas[s] + att0[o];
}

// ---------------- fused spatial mixing ----------------------------------------
__global__ __launch_bounds__(256) void vmix_all(
    const float* __restrict__ G,      // (M, 768)
    const float* __restrict__ attS,   // (N,V,V,S)
    const float* __restrict__ bias,   // (C)
    float* __restrict__ P)            // (N,V,TC)
{
    const int n = blockIdx.y;
    const int t = blockIdx.x;         // 0..63
    const int c = threadIdx.x;        // 0..255
    __shared__ float a[3][V_ * V_];
    for (int l = threadIdx.x; l < V_ * V_ * S_; l += 256) {
        int uv = l / S_, s = l % S_;
        a[s][uv] = attS[((long)n * V_ * V_ + uv) * S_ + s];
    }
    __syncthreads();
    float acc[V_] = {};
    for (int u = 0; u < V_; ++u) {
        const float* g = G + ((long)((n * V_ + u) * T_) + t) * 768 + c;
        float v0 = g[0], v1 = g[256], v2 = g[512];
        const float* a0 = &a[0][u * V_], *a1 = &a[1][u * V_], *a2 = &a[2][u * V_];
        #pragma unroll
        for (int v = 0; v < V_; ++v)
            acc[v] += a0[v] * v0 + a1[v] * v1 + a2[v] * v2;
    }
    const float b = bias[c];
    for (int v = 0; v < V_; ++v)
        P[((long)(n * V_ + v) * T_ + t) * C_ + c] = acc[v] + b;
}

// ---------------- QKT repack: (N,T,V,ci,8chan) f32 -> 8 k-major bf16 planes ---
// plane[chan][n*T+t][v*64+ci], hi and lo
__global__ void qkt_repack(const float* __restrict__ QKT,
                           ushort* __restrict__ QPh, ushort* __restrict__ QPl) {
    long idx = (long)blockIdx.x * 256 + threadIdx.x;   // over M_*CI_
    if (idx >= (long)M_ * CI_) return;
    int m = (int)(idx >> 6), ci = (int)(idx & 63);
    int n = m / (T_ * V_);
    int rem = m % (T_ * V_);
    int t = rem / V_, v = rem % V_;
    const float* src = QKT + (long)m * 512 + ci * 8;
    float4 s0 = *(const float4*)src;
    float4 s1 = *(const float4*)(src + 4);
    float f[8] = {s0.x, s0.y, s0.z, s0.w, s1.x, s1.y, s1.z, s1.w};
    long rowk = ((long)(n * T_ + t)) * 1600 + v * 64 + ci;
    #pragma unroll
    for (int chan = 0; chan < 8; ++chan) {
        ushort h = f2bf(f[chan]);
        QPh[(long)chan * PLANE_ + rowk] = h;
        QPl[(long)chan * PLANE_ + rowk] = f2bf(f[chan] - bf2f(h));
    }
}

// ---------------- temporal attention scores via bf16x3 MFMA -------------------
// block (ks, pair, n): partial[ks][n][pair][t][q] = sum_{k in split} Q[t][k]*K[q][k]
__global__ __launch_bounds__(256) void att_t_mfma(
    const ushort* __restrict__ QPh, const ushort* __restrict__ QPl,
    float* __restrict__ part)
{
    const int ks = blockIdx.x, pair = blockIdx.y, n = blockIdx.z;
    const int kbeg = (ks * 50) / 4, kend = ((ks + 1) * 50) / 4;   // 50 k-steps of 32
    __shared__ ushort Qh[64 * 32], Ql[64 * 32], Kh[64 * 32], Kl[64 * 32];
    const int tid = threadIdx.x;
    const int lane = tid & 63;
    const int wid = tid >> 6, wm = wid >> 1, wn = wid & 1;
    const int fr = lane & 15, fc = lane >> 4;
    const int tr = tid >> 2, tc = tid & 3;
    const long rowoff = ((long)n * T_ + tr) * 1600 + tc * 8;
    const ushort* qh_g = QPh + (long)pair * PLANE_ + rowoff;
    const ushort* ql_g = QPl + (long)pair * PLANE_ + rowoff;
    const ushort* kh_g = QPh + (long)(pair + 4) * PLANE_ + rowoff;
    const ushort* kl_g = QPl + (long)(pair + 4) * PLANE_ + rowoff;
    const int la = lofs(tr, tc);

    uint4 pqh = *(const uint4*)(qh_g + kbeg * 32);
    uint4 pql = *(const uint4*)(ql_g + kbeg * 32);
    uint4 pkh = *(const uint4*)(kh_g + kbeg * 32);
    uint4 pkl = *(const uint4*)(kl_g + kbeg * 32);

    f32x4 acc[2][2] = {};
    for (int kstep = kbeg; kstep < kend; ++kstep) {
        __syncthreads();
        *(uint4*)&Qh[la] = pqh;  *(uint4*)&Ql[la] = pql;
        *(uint4*)&Kh[la] = pkh;  *(uint4*)&Kl[la] = pkl;
        __syncthreads();
        if (kstep + 1 < kend) {
            pqh = *(const uint4*)(qh_g + (kstep + 1) * 32);
            pql = *(const uint4*)(ql_g + (kstep + 1) * 32);
            pkh = *(const uint4*)(kh_g + (kstep + 1) * 32);
            pkl = *(const uint4*)(kl_g + (kstep + 1) * 32);
        }
        bf16x8 ah[2], al[2];
        #pragma unroll
        for (int i = 0; i < 2; ++i) {
            int rA = wm * 32 + i * 16 + fr;
            int oA = lofs(rA, fc);
            ah[i] = *(bf16x8*)&Qh[oA];
            al[i] = *(bf16x8*)&Ql[oA];
        }
        #pragma unroll
        for (int j = 0; j < 2; ++j) {
            int rB = wn * 32 + j * 16 + fr;
            int oB = lofs(rB, fc);
            bf16x8 bh = *(bf16x8*)&Kh[oB];
            bf16x8 bl = *(bf16x8*)&Kl[oB];
            #pragma unroll
            for (int i = 0; i < 2; ++i) {
                acc[i][j] = __builtin_amdgcn_mfma_f32_16x16x32_bf16(ah[i], bh, acc[i][j], 0, 0, 0);
                acc[i][j] = __builtin_amdgcn_mfma_f32_16x16x32_bf16(ah[i], bl, acc[i][j], 0, 0, 0);
                acc[i][j] = __builtin_amdgcn_mfma_f32_16x16x32_bf16(al[i], bh, acc[i][j], 0, 0, 0);
            }
        }
    }
    float* pb = part + (((long)ks * N_ + n) * 4 + pair) * 4096;
    #pragma unroll
    for (int i = 0; i < 2; ++i)
        #pragma unroll
        for (int r = 0; r < 4; ++r) {
            int t = wm * 32 + i * 16 + fc * 4 + r;
            #pragma unroll
            for (int j = 0; j < 2; ++j) {
                int q = wn * 32 + j * 16 + fr;
                pb[t * 64 + q] = acc[i][j][r];
            }
        }
}

// ---------------- finish temporal attention: reduce + tanh + mask -------------
__global__ void att_t_final(const float* __restrict__ part,
                            const float* __restrict__ alphat_f,
                            const float* __restrict__ alphat_b,
                            float* __restrict__ attF, float* __restrict__ attB) {
    int idx = blockIdx.x * 256 + threadIdx.x;   // N*4*4096
    if (idx >= N_ * 4 * 4096) return;
    int n = idx >> 14;
    int rem = idx & 16383;
    int p = rem >> 12, tq = rem & 4095;
    int t = tq >> 6, q = tq & 63;
    const long stride = (long)N_ * 4 * 4096;
    float sum = 0.f;
    #pragma unroll
    for (int ks = 0; ks < 4; ++ks) sum += part[ks * stride + idx];
    float val = tanhf(sum * (1.0f / (CI_ * V_)));
    if (p < 2) {
        float m = (t >= q) ? 1.0f : 0.0f;
        attF[((long)(n * 2 + p)) * 4096 + tq] = val * alphat_f[p] * m;
    } else {
        float m = (q >= t) ? 1.0f : 0.0f;
        attB[((long)(n * 2 + (p - 2))) * 4096 + tq] = val * alphat_b[p - 2] * m;
    }
}

// ---------------- fused temporal mixing ---------------------------------------
template <bool INIT>
__global__ __launch_bounds__(256) void tmix_all(
    const float* __restrict__ G,      // (M, 512) rows (n*T+t)*V+v
    const float* __restrict__ att,    // (N,2,T,T)
    const float* __restrict__ bias,   // (C) or null
    float* __restrict__ P)            // (N,T,VC)
{
    const int n = blockIdx.y;
    const int col = blockIdx.x * 64 + (threadIdx.x & 63);  // 0..VC-1
    const int ty = threadIdx.x >> 6;                       // 0..3
    const int v = col >> 8, c = col & 255;
    __shared__ float a[2 * T_ * T_];
    for (int l = threadIdx.x; l < 2 * T_ * T_; l += 256)
        a[l] = att[(long)n * 2 * T_ * T_ + l];
    __syncthreads();
    float acc[16] = {};
    for (int t = 0; t < T_; ++t) {
        const float* g = G + ((long)((n * T_ + t) * V_) + v) * 512 + c;
        float v0 = g[0], v1 = g[256];
        const float* ar0 = &a[t * T_ + ty * 16];
        const float* ar1 = ar0 + T_ * T_;
        #pragma unroll
        for (int i = 0; i < 16; ++i) acc[i] += ar0[i] * v0 + ar1[i] * v1;
    }
    for (int i = 0; i < 16; ++i) {
        int q = ty * 16 + i;
        long idx = ((long)n * T_ + q) * VC_ + col;
        if (INIT) P[idx] = acc[i] + bias[c];
        else      P[idx] += acc[i];
    }
}

// ---------------- LayerNorm over (T,C) per (n,v) ------------------------------
template <bool TR>
__global__ __launch_bounds__(256) void ln_res_gelu_TC(
    const float* __restrict__ P, const float* __restrict__ X,
    const float* __restrict__ G, const float* __restrict__ B,
    float* __restrict__ Out)
{
    const int g = blockIdx.x;          // n*V+v
    const int n = g / V_, v = g % V_;
    const float* p = P + (long)g * TC_;
    const float* x = X + (long)g * TC_;
    float s = 0.f, ss = 0.f;
    for (int i = threadIdx.x; i < TC_; i += 256) { float a = p[i]; s += a; ss += a * a; }
    __shared__ float rs[4], rss[4];
    #pragma unroll
    for (int off = 32; off > 0; off >>= 1) { s += __shfl_down(s, off); ss += __shfl_down(ss, off); }
    if ((threadIdx.x & 63) == 0) { rs[threadIdx.x >> 6] = s; rss[threadIdx.x >> 6] = ss; }
    __syncthreads();
    s = rs[0] + rs[1] + rs[2] + rs[3];
    ss = rss[0] + rss[1] + rss[2] + rss[3];
    const float mean = s * (1.0f / TC_);
    const float var  = ss * (1.0f / TC_) - mean * mean;
    const float rstd = rsqrtf(var + 1e-5f);
    for (int i = threadIdx.x; i < TC_; i += 256) {
        float val = (p[i] - mean) * rstd * G[i] + B[i];
        float r = gelu_f(x[i] + val);
        if (TR) {
            int t = i >> 8, c = i & 255;
            Out[(((long)n * T_ + t) * V_ + v) * C_ + c] = r;   // write (N,T,V,C)
        } else {
            Out[(long)g * TC_ + i] = r;
        }
    }
}

// ---------------- LayerNorm over (V,C) per (n,t) ------------------------------
__global__ __launch_bounds__(256) void ln_res_gelu_VC(
    const float* __restrict__ P, const float* __restrict__ X,
    const float* __restrict__ G, const float* __restrict__ B,
    float* __restrict__ Out)
{
    const int g = blockIdx.x;          // n*T+t
    const float* p = P + (long)g * VC_;
    const float* x = X + (long)g * VC_;
    float s = 0.f, ss = 0.f;
    for (int i = threadIdx.x; i < VC_; i += 256) { float a = p[i]; s += a; ss += a * a; }
    __shared__ float rs[4], rss[4];
    #pragma unroll
    for (int off = 32; off > 0; off >>= 1) { s += __shfl_down(s, off); ss += __shfl_down(ss, off); }
    if ((threadIdx.x & 63) == 0) { rs[threadIdx.x >> 6] = s; rss[threadIdx.x >> 6] = ss; }
    __syncthreads();
    s = rs[0] + rs[1] + rs[2] + rs[3];
    ss = rss[0] + rss[1] + rss[2] + rss[3];
    const float mean = s * (1.0f / VC_);
    const float var  = ss * (1.0f / VC_) - mean * mean;
    const float rstd = rsqrtf(var + 1e-5f);
    for (int i = threadIdx.x; i < VC_; i += 256) {
        float val = (p[i] - mean) * rstd * G[i] + B[i];
        Out[(long)g * VC_ + i] = gelu_f(x[i] + val);
    }
}

// ==============================================================================
extern "C" void kernel_launch(void* const* d_in, const int* in_sizes, int n_in,
                              void* d_out, int out_size, void* d_ws, size_t ws_size,
                              hipStream_t stream)
{
    const float* x        = (const float*)d_in[0];
    const float* Wqk_s    = (const float*)d_in[1];
    const float* bqk_s    = (const float*)d_in[2];
    const float* alphas   = (const float*)d_in[3];
    const float* att0s    = (const float*)d_in[4];
    const float* Wo_s     = (const float*)d_in[5];
    const float* bo_s     = (const float*)d_in[6];
    const float* g_os     = (const float*)d_in[7];
    const float* b_os     = (const float*)d_in[8];
    const float* Wff_s    = (const float*)d_in[9];
    const float* bff_s    = (const float*)d_in[10];
    const float* g_ffs    = (const float*)d_in[11];
    const float* b_ffs    = (const float*)d_in[12];
    const float* Wqk_t    = (const float*)d_in[13];
    const float* bqk_t    = (const float*)d_in[14];
    const float* alphat_f = (const float*)d_in[15];
    const float* alphat_b = (const float*)d_in[16];
    const float* Wo_t     = (const float*)d_in[17];
    const float* bo_t     = (const float*)d_in[18];
    const float* g_ot     = (const float*)d_in[19];
    const float* b_ot     = (const float*)d_in[20];
    const float* Wff_t    = (const float*)d_in[21];
    const float* bff_t    = (const float*)d_in[22];
    const float* g_fft    = (const float*)d_in[23];
    const float* b_fft    = (const float*)d_in[24];
    const float* conv_w   = (const float*)d_in[25];
    const float* conv_b   = (const float*)d_in[26];
    const float* bn_g     = (const float*)d_in[27];
    const float* bn_b     = (const float*)d_in[28];
    const float* bn_m     = (const float*)d_in[29];
    const float* bn_v     = (const float*)d_in[30];

    float* B  = (float*)d_ws;
    float* B0  = B;
    float* B13 = B + TOT_;            // +13.1M
    float* B26 = B + 2 * TOT_;        // +26.2M
    float* B39 = B + 3 * TOT_;        // +39.3M
    float* RA  = B + 4 * TOT_;        // +52.4M small buffers
    float* attPre = RA;                               // 60,000
    float* attS   = attPre + N_*V_*V_*S_;             // 60,000
    float* attF   = attS   + N_*V_*V_*S_;             // 262,144
    float* attB   = attF   + (long)N_*2*T_*T_;        // 262,144
    float* part   = attB   + (long)N_*2*T_*T_;        // 4*N*4*4096 = 2,097,152
    // bf16 weight planes (ushort), after part
    ushort* wp = (ushort*)(part + 4L*N_*4*4096);
    ushort* qs_h = wp;  wp += 384*256;   ushort* qs_l = wp;  wp += 384*256;
    ushort* os_h = wp;  wp += 768*256;   ushort* os_l = wp;  wp += 768*256;
    ushort* fs_h = wp;  wp += 256*256;   ushort* fs_l = wp;  wp += 256*256;
    ushort* qt_h = wp;  wp += 512*256;   ushort* qt_l = wp;  wp += 512*256;
    ushort* ot0_h= wp;  wp += 512*256;   ushort* ot0_l= wp;  wp += 512*256;
    ushort* ot1_h= wp;  wp += 512*256;   ushort* ot1_l= wp;  wp += 512*256;
    ushort* ft_h = wp;  wp += 256*256;   ushort* ft_l = wp;  wp += 256*256;
    ushort* cv_h = wp;  wp += K_*256*256; ushort* cv_l = wp;
    // QKT bf16 planes live in B26..B52 (dead space after repack consumes QKT f32)
    ushort* QPh = (ushort*)B26;
    ushort* QPl = QPh + 8 * PLANE_;
    float* YT = (float*)d_out;        // y^T (N,T,V,C); overwritten at the end

    // ---- weight preconversion (hi/lo bf16, transposed [N][K]) ----
    auto prepw = [&](const float* W, int Kc, int Nc, ushort* h, ushort* l) {
        prep_w<<<(Kc*Nc + 255)/256, 256, 0, stream>>>(W, Kc, Nc, h, l);
    };
    prepw(Wqk_s, C_, 384, qs_h, qs_l);
    prepw(Wo_s,  C_, 768, os_h, os_l);
    prepw(Wff_s, C_, 256, fs_h, fs_l);
    prepw(Wqk_t, C_, 512, qt_h, qt_l);
    prepw(Wo_t,                      C_, 512, ot0_h, ot0_l);
    prepw(Wo_t + (long)ST_*C_*C_,    C_, 512, ot1_h, ot1_l);
    prepw(Wff_t, C_, 256, ft_h, ft_l);
    prep_conv<<<(K_*C_*C_ + 255)/256, 256, 0, stream>>>(conv_w, cv_h, cv_l);

    // ---- Stage 1: spatial ----
    gemm_mfma<<<dim3(384/128, M_/128), 256, 0, stream>>>(x, C_, qs_h, qs_l, C_, bqk_s, B0, 384);
    zero_f32<<<(N_*V_*V_*S_ + 255)/256, 256, 0, stream>>>(attPre, N_*V_*V_*S_);
    att_s_partial<<<dim3(N_, 8), 256, 0, stream>>>(B0, attPre);
    att_s_final<<<(N_*V_*V_*S_ + 255)/256, 256, 0, stream>>>(attPre, alphas, att0s, attS);
    gemm_mfma<<<dim3(768/128, M_/128), 256, 0, stream>>>(x, C_, os_h, os_l, C_, nullptr, B0, 768);
    vmix_all<<<dim3(T_, N_), 256, 0, stream>>>(B0, attS, bo_s, B39);
    ln_res_gelu_TC<false><<<N_*V_, 256, 0, stream>>>(B39, x, g_os, b_os, B0);
    gemm_mfma<<<dim3(256/128, M_/128), 256, 0, stream>>>(B0, C_, fs_h, fs_l, C_, bff_s, B13, 256);
    ln_res_gelu_TC<true><<<N_*V_, 256, 0, stream>>>(B13, x, g_ffs, b_ffs, YT);

    // ---- Stage 2: temporal ----
    gemm_mfma<<<dim3(512/128, M_/128), 256, 0, stream>>>(YT, C_, qt_h, qt_l, C_, bqk_t, B0, 512);
    qkt_repack<<<(int)(((long)M_*CI_ + 255)/256), 256, 0, stream>>>(B0, QPh, QPl);
    att_t_mfma<<<dim3(4, 4, N_), 256, 0, stream>>>(QPh, QPl, part);
    att_t_final<<<(N_*4*4096 + 255)/256, 256, 0, stream>>>(part, alphat_f, alphat_b, attF, attB);
    gemm_mfma<<<dim3(512/128, M_/128), 256, 0, stream>>>(YT, C_, ot0_h, ot0_l, C_, nullptr, B26, 512);
    tmix_all<true><<<dim3(VC_/64, N_), 256, 0, stream>>>(B26, attF, bo_t, B0);
    gemm_mfma<<<dim3(512/128, M_/128), 256, 0, stream>>>(YT, C_, ot1_h, ot1_l, C_, nullptr, B26, 512);
    tmix_all<false><<<dim3(VC_/64, N_), 256, 0, stream>>>(B26, attB, nullptr, B0);
    ln_res_gelu_VC<<<N_*T_, 256, 0, stream>>>(B0, YT, g_ot, b_ot, B13);
    gemm_mfma<<<dim3(256/128, M_/128), 256, 0, stream>>>(B13, C_, ft_h, ft_l, C_, bff_t, B26, 256);
    ln_res_gelu_VC<<<N_*T_, 256, 0, stream>>>(B26, YT, g_fft, b_fft, B39);

    // ---- Stage 3: conv + BN + gelu + transpose ----
    conv_bn_gelu<<<dim3(C_/128, M_/128), 256, 0, stream>>>(B39, cv_h, cv_l, conv_b, bn_g, bn_b, bn_m, bn_v, (float*)d_out);
}